// Round 1
// baseline (527.815 us; speedup 1.0000x reference)
//
#include <hip/hip_runtime.h>
#include <hip/hip_bf16.h>
#include <cstdint>
#include <cstddef>

// ---------------- types / helpers ----------------
typedef __attribute__((ext_vector_type(8))) short short8;   // 8 x bf16 (4 VGPRs)
typedef __attribute__((ext_vector_type(4))) float f32x4;    // MFMA accumulator
typedef __attribute__((ext_vector_type(4))) unsigned short us4;

#define MFMA_BF16(a, b, c) __builtin_amdgcn_mfma_f32_16x16x32_bf16((a), (b), (c), 0, 0, 0)

__device__ __forceinline__ unsigned short f2bf(float f) {  // fp32 -> bf16 RNE
  unsigned int u = __float_as_uint(f);
  u += 0x7FFFu + ((u >> 16) & 1u);
  return (unsigned short)(u >> 16);
}

#if defined(__has_builtin)
#if __has_builtin(__builtin_amdgcn_global_load_lds)
#define HAVE_GLL 1
#endif
#endif

#ifdef HAVE_GLL
typedef const void __attribute__((address_space(1)))* as1_cvp;
typedef void __attribute__((address_space(3)))* as3_vp;
__device__ __forceinline__ void gll16(const short* g, short* l) {
  // 16B per lane; LDS dest is wave-uniform base + lane*16
  __builtin_amdgcn_global_load_lds((as1_cvp)g, (as3_vp)l, 16, 0, 0);
}
#endif

// ---------------- prep kernels ----------------
__global__ void count_kernel(const int* __restrict__ cm, int* __restrict__ counts) {
  __shared__ int sd[256];
  const int b = blockIdx.x, t = threadIdx.x;
  int s = 0;
  for (int i = t; i < 1024; i += 256) s += cm[b * 1024 + i];
  sd[t] = s; __syncthreads();
  for (int k = 128; k > 0; k >>= 1) { if (t < k) sd[t] += sd[t + k]; __syncthreads(); }
  if (t == 0) counts[b] = sd[0];
}

__global__ void pack_bias_kernel(const float* __restrict__ bq, const float* __restrict__ bk,
                                 const float* __restrict__ bv, float* __restrict__ dst) {
  int i = blockIdx.x * 256 + threadIdx.x;
  dst[i] = (i < 1024) ? bq[i] : (i < 2048 ? bk[i - 1024] : bv[i - 2048]);
}

// src fp32 [R][C] -> dst bf16 [C][R]
__global__ void transpose_kernel(const float* __restrict__ src, unsigned short* __restrict__ dst,
                                 int R, int C) {
  __shared__ float tile[32][33];
  const int c0 = blockIdx.x * 32, r0 = blockIdx.y * 32;
  const int tx = threadIdx.x, ty = threadIdx.y;
  #pragma unroll
  for (int i = ty; i < 32; i += 8)
    tile[i][tx] = src[(size_t)(r0 + i) * C + (c0 + tx)];
  __syncthreads();
  #pragma unroll
  for (int i = ty; i < 32; i += 8)
    dst[(size_t)(c0 + i) * R + (r0 + tx)] = f2bf(tile[tx][i]);
}

// LayerNorm over rows of 1024 fp32 -> bf16
__global__ __launch_bounds__(256) void ln_kernel(const float* __restrict__ in,
                                                 const float* __restrict__ gw,
                                                 const float* __restrict__ bw,
                                                 unsigned short* __restrict__ out) {
  const int row = blockIdx.x, t = threadIdx.x;
  const float4 v = ((const float4*)(in + (size_t)row * 1024))[t];
  float s = v.x + v.y + v.z + v.w;
  float ss = v.x * v.x + v.y * v.y + v.z * v.z + v.w * v.w;
  #pragma unroll
  for (int o = 32; o >= 1; o >>= 1) { s += __shfl_down(s, o, 64); ss += __shfl_down(ss, o, 64); }
  __shared__ float red[8];
  if ((t & 63) == 0) { red[t >> 6] = s; red[4 + (t >> 6)] = ss; }
  __syncthreads();
  const float S  = red[0] + red[1] + red[2] + red[3];
  const float SS = red[4] + red[5] + red[6] + red[7];
  const float mu = S * (1.0f / 1024.0f);
  const float var = SS * (1.0f / 1024.0f) - mu * mu;
  const float rs = rsqrtf(var + 1e-5f);
  const int c = t * 4;
  const float4 g4 = ((const float4*)gw)[t];
  const float4 b4 = ((const float4*)bw)[t];
  us4 o4;
  o4[0] = f2bf((v.x - mu) * rs * g4.x + b4.x);
  o4[1] = f2bf((v.y - mu) * rs * g4.y + b4.y);
  o4[2] = f2bf((v.z - mu) * rs * g4.z + b4.z);
  o4[3] = f2bf((v.w - mu) * rs * g4.w + b4.w);
  *(us4*)(out + (size_t)row * 1024 + c) = o4;
}

// ---------------- GEMM: C[M,N] = A[M,K] (bf16) * BT[N,K]^T (bf16) + bias ----------------
// 128x128 tile, BK=32, 256 threads (4 waves 2x2), 16x16x32 bf16 MFMA.
// EPI 0: out bf16; EPI 1: gelu -> bf16; EPI 2: + res(fp32) -> fp32
template <int EPI>
__global__ __launch_bounds__(256) void gemm_bt_kernel(
    const short* __restrict__ A, const short* __restrict__ BT,
    const float* __restrict__ bias, int N, int K,
    unsigned short* __restrict__ outb, float* __restrict__ outf,
    const float* __restrict__ res) {
  __shared__ alignas(16) short As[4096];
  __shared__ alignas(16) short Bs[4096];
  const int t = threadIdx.x;
  const int l = t & 63, w = t >> 6;
  const int lq = l & 15, g = l >> 4;
  const int wr = w >> 1, wc = w & 1;
  const int bm = blockIdx.x * 128, bn = blockIdx.y * 128;

  const f32x4 z4 = {0.f, 0.f, 0.f, 0.f};
  f32x4 acc[4][4];
  #pragma unroll
  for (int i = 0; i < 4; i++)
    #pragma unroll
    for (int j = 0; j < 4; j++) acc[i][j] = z4;

  const short* ga = A  + (size_t)(bm + (t >> 2)) * K + (t & 3) * 8;
  const short* gb = BT + (size_t)(bn + (t >> 2)) * K + (t & 3) * 8;
  short* lA = As + w * 512;  // wave-uniform LDS base
  short* lB = Bs + w * 512;

  for (int k0 = 0; k0 < K; k0 += 32) {
#ifdef HAVE_GLL
    gll16(ga + k0,                     lA);
    gll16(ga + k0 + (size_t)64 * K,    lA + 2048);
    gll16(gb + k0,                     lB);
    gll16(gb + k0 + (size_t)64 * K,    lB + 2048);
#else
    short8 v0 = *(const short8*)(ga + k0);
    short8 v1 = *(const short8*)(ga + k0 + (size_t)64 * K);
    short8 v2 = *(const short8*)(gb + k0);
    short8 v3 = *(const short8*)(gb + k0 + (size_t)64 * K);
    *(short8*)(As + t * 8) = v0;
    *(short8*)(As + 2048 + t * 8) = v1;
    *(short8*)(Bs + t * 8) = v2;
    *(short8*)(Bs + 2048 + t * 8) = v3;
#endif
    __syncthreads();
    short8 af[4], bfr[4];
    #pragma unroll
    for (int mi = 0; mi < 4; mi++)
      af[mi] = *(const short8*)(As + (wr * 64 + mi * 16 + lq) * 32 + 8 * g);
    #pragma unroll
    for (int ni = 0; ni < 4; ni++)
      bfr[ni] = *(const short8*)(Bs + (wc * 64 + ni * 16 + lq) * 32 + 8 * g);
    #pragma unroll
    for (int mi = 0; mi < 4; mi++)
      #pragma unroll
      for (int ni = 0; ni < 4; ni++)
        acc[mi][ni] = MFMA_BF16(af[mi], bfr[ni], acc[mi][ni]);
    __syncthreads();
  }

  #pragma unroll
  for (int mi = 0; mi < 4; mi++) {
    #pragma unroll
    for (int ni = 0; ni < 4; ni++) {
      const int col = bn + wc * 64 + ni * 16 + lq;
      const float bv = bias[col];
      #pragma unroll
      for (int r = 0; r < 4; r++) {
        const int row = bm + wr * 64 + mi * 16 + 4 * g + r;
        float v = acc[mi][ni][r] + bv;
        const size_t idx = (size_t)row * N + col;
        if (EPI == 1) v = 0.5f * v * (1.0f + erff(v * 0.70710678118654752440f));
        if (EPI == 2) outf[idx] = v + res[idx];
        else          outb[idx] = f2bf(v);
      }
    }
  }
}

// ---------------- flash attention ----------------
// qkv: [B*T, 3072] bf16 rows = [q(0:1024) | k(1024:2048) | v(2048:3072)], head h at h*64.
// Mask: col<256 -> col<counts[b]; col>=256 -> row>=256 && col<=row.
// One block = (qtile of 64 rows) x (b,h). 4 waves, 16 q-rows each.
// Swapped QK^T: S^T = mfma(K, Q); permuted K rows so P^T feeds PV B-operand in-lane.
__global__ __launch_bounds__(256) void attn_kernel(
    const short* __restrict__ qkv, unsigned short* __restrict__ y,
    const int* __restrict__ counts) {
  const int qt = blockIdx.x, bh = blockIdx.y;
  const int b = bh >> 4, h = bh & 15;
  const int t = threadIdx.x, w = t >> 6, l = t & 63;
  const int lq = l & 15, g = l >> 4;
  const int qw = qt * 64 + w * 16;
  const int count = counts[b];
  const int q = qw + lq;

  const short* base = qkv + (size_t)b * 1024 * 3072 + h * 64;

  short8 qf0, qf1;  // Q fragment (B-operand), lane: Q[qw+lq][8g..8g+7 (+32)]
  {
    const short* qr = base + (size_t)(qw + lq) * 3072 + 8 * g;
    qf0 = *(const short8*)qr;
    qf1 = *(const short8*)(qr + 32);
  }

  __shared__ alignas(16) short VT[64][40];  // V^T tile [d][kv], pad 8

  const f32x4 z4 = {0.f, 0.f, 0.f, 0.f};
  f32x4 oacc[4] = {z4, z4, z4, z4};  // O^T: d = 16*dc + 4g + r, col q = lq
  float m_run = -1e30f, l_run = 0.f;
  const int permrow = 8 * (lq >> 2) + (lq & 3);  // K-row permutation -> P^T in-lane for PV

  auto process = [&](int kv0, bool causal, bool compute) {
    {  // stage V^T cooperatively (all 256 threads)
      const int kv = t >> 3, dbase = (t & 7) * 8;
      const short8 vv = *(const short8*)(base + (size_t)(kv0 + kv) * 3072 + 2048 + dbase);
      #pragma unroll
      for (int i = 0; i < 8; i++) VT[dbase + i][kv] = vv[i];
    }
    __syncthreads();
    if (compute) {
      const short* ka = base + (size_t)(kv0 + permrow) * 3072 + 1024 + 8 * g;
      const short* kb = ka + 4 * 3072;
      f32x4 sA = z4, sB = z4;  // S^T: lane holds kv = kv0+8g+r (A) / +4 (B), col q = lq
      sA = MFMA_BF16(*(const short8*)ka,        qf0, sA);
      sA = MFMA_BF16(*(const short8*)(ka + 32), qf1, sA);
      sB = MFMA_BF16(*(const short8*)kb,        qf0, sB);
      sB = MFMA_BF16(*(const short8*)(kb + 32), qf1, sB);
      float mx = -1e30f;
      #pragma unroll
      for (int r = 0; r < 4; r++) {
        const int colA = kv0 + 8 * g + r, colB = colA + 4;
        float vA = sA[r] * 0.125f, vB = sB[r] * 0.125f;
        const bool okA = causal ? (colA <= q) : (colA < count);
        const bool okB = causal ? (colB <= q) : (colB < count);
        vA = okA ? vA : -1e30f;
        vB = okB ? vB : -1e30f;
        sA[r] = vA; sB[r] = vB;
        mx = fmaxf(mx, fmaxf(vA, vB));
      }
      mx = fmaxf(mx, __shfl_xor(mx, 16, 64));
      mx = fmaxf(mx, __shfl_xor(mx, 32, 64));
      const float m_new = fmaxf(m_run, mx);
      const float sf = __expf(m_run - m_new);
      float ps = 0.f;
      #pragma unroll
      for (int r = 0; r < 4; r++) {
        const float a  = __expf(sA[r] - m_new);
        const float c2 = __expf(sB[r] - m_new);
        sA[r] = a; sB[r] = c2; ps += a + c2;
      }
      ps += __shfl_xor(ps, 16, 64);
      ps += __shfl_xor(ps, 32, 64);
      l_run = l_run * sf + ps;
      m_run = m_new;
      short8 pf;  // P^T B-operand: elem j -> kv = 8g+j, col q = lq  (in-lane thanks to permrow)
      pf[0] = (short)f2bf(sA[0]); pf[1] = (short)f2bf(sA[1]);
      pf[2] = (short)f2bf(sA[2]); pf[3] = (short)f2bf(sA[3]);
      pf[4] = (short)f2bf(sB[0]); pf[5] = (short)f2bf(sB[1]);
      pf[6] = (short)f2bf(sB[2]); pf[7] = (short)f2bf(sB[3]);
      #pragma unroll
      for (int dc = 0; dc < 4; dc++) {
        #pragma unroll
        for (int r = 0; r < 4; r++) oacc[dc][r] *= sf;
        const short8 vf = *(const short8*)&VT[16 * dc + lq][8 * g];  // V^T[d][kv]
        oacc[dc] = MFMA_BF16(vf, pf, oacc[dc]);
      }
    }
    __syncthreads();
  };

  // cond region: cols [0,256), visible iff col < count (count >= 1)
  for (int kv0 = 0; kv0 < 256; kv0 += 32) {
    if (kv0 >= count) break;  // block-uniform
    process(kv0, false, true);
  }
  // causal region: cols [256, qt*64+64), visible iff col <= row
  if (qt >= 4) {
    const int kv_end = qt * 64 + 64;
    for (int kv0 = 256; kv0 < kv_end; kv0 += 32)
      process(kv0, true, kv0 <= qw + 15);
  }

  const float inv = 1.0f / l_run;
  unsigned short* yr = y + (size_t)(b * 1024 + qw + lq) * 1024 + h * 64;
  #pragma unroll
  for (int dc = 0; dc < 4; dc++)
    #pragma unroll
    for (int r = 0; r < 4; r++)
      yr[16 * dc + 4 * g + r] = f2bf(oacc[dc][r] * inv);
}

// ---------------- launch ----------------
// Workspace layout (needs ~152.1 MB):
//  [0,16M)   xn bf16            (phase 1) | [0,64M) act bf16 (phase 2, after attn)
//  [16M,64M) qkv bf16
//  [64M,80M) y bf16
//  [80M,112M) x1 fp32
//  [112M,128M) h bf16
//  [128M,134M) WqkvT | [134M,136M) WpT | [136M,144M) W1T | [144M,152M) W2T  (bf16)
//  [152M, +12KB) bqkv fp32 | [152M+16KB, +32B) counts
extern "C" void kernel_launch(void* const* d_in, const int* in_sizes, int n_in,
                              void* d_out, int out_size, void* d_ws, size_t ws_size,
                              hipStream_t stream) {
  (void)in_sizes; (void)n_in; (void)out_size; (void)ws_size;
  const float* x     = (const float*)d_in[0];
  const float* ln1_g = (const float*)d_in[1];
  const float* ln1_b = (const float*)d_in[2];
  const float* Wq    = (const float*)d_in[3];
  const float* bq    = (const float*)d_in[4];
  const float* Wk    = (const float*)d_in[5];
  const float* bk    = (const float*)d_in[6];
  const float* Wv    = (const float*)d_in[7];
  const float* bv    = (const float*)d_in[8];
  const float* Wp    = (const float*)d_in[9];
  const float* bp    = (const float*)d_in[10];
  const float* ln2_g = (const float*)d_in[11];
  const float* ln2_b = (const float*)d_in[12];
  const float* W1    = (const float*)d_in[13];
  const float* b1    = (const float*)d_in[14];
  const float* W2    = (const float*)d_in[15];
  const float* b2    = (const float*)d_in[16];
  const int* cond_mask = (const int*)d_in[17];
  // cond_len=256 / token_len=768 hardcoded (mask simplifies to cond-prefix + causal)

  char* ws = (char*)d_ws;
  const size_t MB = 1u << 20;
  short* xn    = (short*)(ws + 0);
  short* qkv   = (short*)(ws + 16 * MB);
  short* act   = (short*)(ws + 0);
  unsigned short* yb = (unsigned short*)(ws + 64 * MB);
  float* x1    = (float*)(ws + 80 * MB);
  short* hb    = (short*)(ws + 112 * MB);
  short* wqkvT = (short*)(ws + 128 * MB);
  short* wpT   = (short*)(ws + 134 * MB);
  short* w1T   = (short*)(ws + 136 * MB);
  short* w2T   = (short*)(ws + 144 * MB);
  float* bqkv  = (float*)(ws + 152 * MB);
  int* counts  = (int*)(ws + 152 * MB + 16384);

  const dim3 tb(32, 8);
  count_kernel<<<8, 256, 0, stream>>>(cond_mask, counts);
  pack_bias_kernel<<<12, 256, 0, stream>>>(bq, bk, bv, bqkv);
  transpose_kernel<<<dim3(32, 32), tb, 0, stream>>>(Wq, (unsigned short*)wqkvT, 1024, 1024);
  transpose_kernel<<<dim3(32, 32), tb, 0, stream>>>(Wk, (unsigned short*)(wqkvT + 1024 * 1024), 1024, 1024);
  transpose_kernel<<<dim3(32, 32), tb, 0, stream>>>(Wv, (unsigned short*)(wqkvT + 2 * 1024 * 1024), 1024, 1024);
  transpose_kernel<<<dim3(32, 32), tb, 0, stream>>>(Wp, (unsigned short*)wpT, 1024, 1024);
  transpose_kernel<<<dim3(128, 32), tb, 0, stream>>>(W1, (unsigned short*)w1T, 1024, 4096);
  transpose_kernel<<<dim3(32, 128), tb, 0, stream>>>(W2, (unsigned short*)w2T, 4096, 1024);
  ln_kernel<<<8192, 256, 0, stream>>>(x, ln1_g, ln1_b, (unsigned short*)xn);

  gemm_bt_kernel<0><<<dim3(64, 24), 256, 0, stream>>>(xn, wqkvT, bqkv, 3072, 1024,
                                                      (unsigned short*)qkv, nullptr, nullptr);
  attn_kernel<<<dim3(16, 128), 256, 0, stream>>>(qkv, yb, counts);
  gemm_bt_kernel<2><<<dim3(64, 8), 256, 0, stream>>>((const short*)yb, wpT, bp, 1024, 1024,
                                                     nullptr, x1, x);
  ln_kernel<<<8192, 256, 0, stream>>>(x1, ln2_g, ln2_b, (unsigned short*)hb);
  gemm_bt_kernel<1><<<dim3(64, 32), 256, 0, stream>>>(hb, w1T, b1, 4096, 1024,
                                                      (unsigned short*)act, nullptr, nullptr);
  gemm_bt_kernel<2><<<dim3(64, 8), 256, 0, stream>>>(act, w2T, b2, 1024, 4096,
                                                     nullptr, (float*)d_out, x1);
}

// Round 2
// 513.601 us; speedup vs baseline: 1.0277x; 1.0277x over previous
//
#include <hip/hip_runtime.h>
#include <hip/hip_bf16.h>
#include <cstdint>
#include <cstddef>

// ---------------- types / helpers ----------------
typedef __attribute__((ext_vector_type(8))) short short8;   // 8 x bf16 (4 VGPRs)
typedef __attribute__((ext_vector_type(4))) float f32x4;    // MFMA accumulator
typedef __attribute__((ext_vector_type(4))) unsigned short us4;

#define MFMA_BF16(a, b, c) __builtin_amdgcn_mfma_f32_16x16x32_bf16((a), (b), (c), 0, 0, 0)

__device__ __forceinline__ unsigned short f2bf(float f) {  // fp32 -> bf16 RNE
  unsigned int u = __float_as_uint(f);
  u += 0x7FFFu + ((u >> 16) & 1u);
  return (unsigned short)(u >> 16);
}

#if defined(__has_builtin)
#if __has_builtin(__builtin_amdgcn_global_load_lds)
#define HAVE_GLL 1
#endif
#endif

#ifdef HAVE_GLL
typedef const void __attribute__((address_space(1)))* as1_cvp;
typedef void __attribute__((address_space(3)))* as3_vp;
__device__ __forceinline__ void gll16(const short* g, short* l) {
  // 16B per lane; LDS dest is wave-uniform base + lane*16
  __builtin_amdgcn_global_load_lds((as1_cvp)g, (as3_vp)l, 16, 0, 0);
}
#endif

// ---------------- prep kernels ----------------
__global__ void count_kernel(const int* __restrict__ cm, int* __restrict__ counts) {
  __shared__ int sd[256];
  const int b = blockIdx.x, t = threadIdx.x;
  int s = 0;
  for (int i = t; i < 1024; i += 256) s += cm[b * 1024 + i];
  sd[t] = s; __syncthreads();
  for (int k = 128; k > 0; k >>= 1) { if (t < k) sd[t] += sd[t + k]; __syncthreads(); }
  if (t == 0) counts[b] = sd[0];
}

__global__ void pack_bias_kernel(const float* __restrict__ bq, const float* __restrict__ bk,
                                 const float* __restrict__ bv, float* __restrict__ dst) {
  int i = blockIdx.x * 256 + threadIdx.x;
  dst[i] = (i < 1024) ? bq[i] : (i < 2048 ? bk[i - 1024] : bv[i - 2048]);
}

// src fp32 [R][C] -> dst bf16 [C][R]
__global__ void transpose_kernel(const float* __restrict__ src, unsigned short* __restrict__ dst,
                                 int R, int C) {
  __shared__ float tile[32][33];
  const int c0 = blockIdx.x * 32, r0 = blockIdx.y * 32;
  const int tx = threadIdx.x, ty = threadIdx.y;
  #pragma unroll
  for (int i = ty; i < 32; i += 8)
    tile[i][tx] = src[(size_t)(r0 + i) * C + (c0 + tx)];
  __syncthreads();
  #pragma unroll
  for (int i = ty; i < 32; i += 8)
    dst[(size_t)(c0 + i) * R + (r0 + tx)] = f2bf(tile[tx][i]);
}

// V^T precompute: qkv [B*T][3072] (V at col 2048 + h*64) -> vtr [B*H][64][1024] bf16
__global__ void vtrans_kernel(const short* __restrict__ qkv, short* __restrict__ vtr) {
  __shared__ short tile[32][33];
  const int bh = blockIdx.z;
  const int t0 = blockIdx.x * 32, d0 = blockIdx.y * 32;
  const int b = bh >> 4, h = bh & 15;
  const int tx = threadIdx.x, ty = threadIdx.y;
  const short* src = qkv + (size_t)b * 1024 * 3072 + 2048 + h * 64;
  #pragma unroll
  for (int i = ty; i < 32; i += 8)
    tile[i][tx] = src[(size_t)(t0 + i) * 3072 + d0 + tx];
  __syncthreads();
  short* dst = vtr + (size_t)bh * 65536;
  #pragma unroll
  for (int i = ty; i < 32; i += 8)
    dst[(d0 + i) * 1024 + t0 + tx] = tile[tx][i];
}

// LayerNorm over rows of 1024 fp32 -> bf16
__global__ __launch_bounds__(256) void ln_kernel(const float* __restrict__ in,
                                                 const float* __restrict__ gw,
                                                 const float* __restrict__ bw,
                                                 unsigned short* __restrict__ out) {
  const int row = blockIdx.x, t = threadIdx.x;
  const float4 v = ((const float4*)(in + (size_t)row * 1024))[t];
  float s = v.x + v.y + v.z + v.w;
  float ss = v.x * v.x + v.y * v.y + v.z * v.z + v.w * v.w;
  #pragma unroll
  for (int o = 32; o >= 1; o >>= 1) { s += __shfl_down(s, o, 64); ss += __shfl_down(ss, o, 64); }
  __shared__ float red[8];
  if ((t & 63) == 0) { red[t >> 6] = s; red[4 + (t >> 6)] = ss; }
  __syncthreads();
  const float S  = red[0] + red[1] + red[2] + red[3];
  const float SS = red[4] + red[5] + red[6] + red[7];
  const float mu = S * (1.0f / 1024.0f);
  const float var = SS * (1.0f / 1024.0f) - mu * mu;
  const float rs = rsqrtf(var + 1e-5f);
  const int c = t * 4;
  const float4 g4 = ((const float4*)gw)[t];
  const float4 b4 = ((const float4*)bw)[t];
  us4 o4;
  o4[0] = f2bf((v.x - mu) * rs * g4.x + b4.x);
  o4[1] = f2bf((v.y - mu) * rs * g4.y + b4.y);
  o4[2] = f2bf((v.z - mu) * rs * g4.z + b4.z);
  o4[3] = f2bf((v.w - mu) * rs * g4.w + b4.w);
  *(us4*)(out + (size_t)row * 1024 + c) = o4;
}

// ---------------- GEMM: C[M,N] = A[M,K] (bf16) * BT[N,K]^T (bf16) + bias ----------------
// 128x128 tile, BK=32, 256 threads (4 waves 2x2), 16x16x32 bf16 MFMA.
// EPI 0: out bf16; EPI 1: gelu -> bf16; EPI 2: + res(fp32) -> fp32
template <int EPI>
__global__ __launch_bounds__(256) void gemm_bt_kernel(
    const short* __restrict__ A, const short* __restrict__ BT,
    const float* __restrict__ bias, int N, int K,
    unsigned short* __restrict__ outb, float* __restrict__ outf,
    const float* __restrict__ res) {
  __shared__ alignas(16) short As[4096];
  __shared__ alignas(16) short Bs[4096];
  const int t = threadIdx.x;
  const int l = t & 63, w = t >> 6;
  const int lq = l & 15, g = l >> 4;
  const int wr = w >> 1, wc = w & 1;
  const int bm = blockIdx.x * 128, bn = blockIdx.y * 128;

  const f32x4 z4 = {0.f, 0.f, 0.f, 0.f};
  f32x4 acc[4][4];
  #pragma unroll
  for (int i = 0; i < 4; i++)
    #pragma unroll
    for (int j = 0; j < 4; j++) acc[i][j] = z4;

  const short* ga = A  + (size_t)(bm + (t >> 2)) * K + (t & 3) * 8;
  const short* gb = BT + (size_t)(bn + (t >> 2)) * K + (t & 3) * 8;
  short* lA = As + w * 512;  // wave-uniform LDS base
  short* lB = Bs + w * 512;

  for (int k0 = 0; k0 < K; k0 += 32) {
#ifdef HAVE_GLL
    gll16(ga + k0,                     lA);
    gll16(ga + k0 + (size_t)64 * K,    lA + 2048);
    gll16(gb + k0,                     lB);
    gll16(gb + k0 + (size_t)64 * K,    lB + 2048);
#else
    short8 v0 = *(const short8*)(ga + k0);
    short8 v1 = *(const short8*)(ga + k0 + (size_t)64 * K);
    short8 v2 = *(const short8*)(gb + k0);
    short8 v3 = *(const short8*)(gb + k0 + (size_t)64 * K);
    *(short8*)(As + t * 8) = v0;
    *(short8*)(As + 2048 + t * 8) = v1;
    *(short8*)(Bs + t * 8) = v2;
    *(short8*)(Bs + 2048 + t * 8) = v3;
#endif
    __syncthreads();
    short8 af[4], bfr[4];
    #pragma unroll
    for (int mi = 0; mi < 4; mi++)
      af[mi] = *(const short8*)(As + (wr * 64 + mi * 16 + lq) * 32 + 8 * g);
    #pragma unroll
    for (int ni = 0; ni < 4; ni++)
      bfr[ni] = *(const short8*)(Bs + (wc * 64 + ni * 16 + lq) * 32 + 8 * g);
    #pragma unroll
    for (int mi = 0; mi < 4; mi++)
      #pragma unroll
      for (int ni = 0; ni < 4; ni++)
        acc[mi][ni] = MFMA_BF16(af[mi], bfr[ni], acc[mi][ni]);
    __syncthreads();
  }

  #pragma unroll
  for (int mi = 0; mi < 4; mi++) {
    #pragma unroll
    for (int ni = 0; ni < 4; ni++) {
      const int col = bn + wc * 64 + ni * 16 + lq;
      const float bv = bias[col];
      #pragma unroll
      for (int r = 0; r < 4; r++) {
        const int row = bm + wr * 64 + mi * 16 + 4 * g + r;
        float v = acc[mi][ni][r] + bv;
        const size_t idx = (size_t)row * N + col;
        if (EPI == 1) v = 0.5f * v * (1.0f + erff(v * 0.70710678118654752440f));
        if (EPI == 2) outf[idx] = v + res[idx];
        else          outb[idx] = f2bf(v);
      }
    }
  }
}

// ---------------- flash attention (no LDS, no barriers) ----------------
// qkv rows [B*T][3072] = [q|k|v]; vtr [B*H][64][1024] = V^T per (b,h).
// One wave owns 32 q rows (2 column-groups of 16). KV tiles of 32, K/V frags
// shared across groups. Swapped QK^T (S^T = mfma(K,Q)) + permuted K rows so
// P^T feeds PV's B-operand with zero cross-lane traffic.
__global__ __launch_bounds__(256) void attn_kernel(
    const short* __restrict__ qkv, const short* __restrict__ vtr,
    unsigned short* __restrict__ y, const int* __restrict__ counts) {
  const int bh = blockIdx.y;
  const int b = bh >> 4, h = bh & 15;
  const int t = threadIdx.x, w = t >> 6, l = t & 63;
  const int lq = l & 15, g = l >> 4;
  const int qw = blockIdx.x * 128 + w * 32;
  const int count = counts[b];

  const short* base  = qkv + (size_t)b * 1024 * 3072 + h * 64;
  const short* vbase = vtr + (size_t)bh * 65536;

  short8 qf[2][2];  // [group][k-half]; B-operand: col q = qw+16*grp+lq
  #pragma unroll
  for (int grp = 0; grp < 2; ++grp) {
    const short* qr = base + (size_t)(qw + grp * 16 + lq) * 3072 + 8 * g;
    qf[grp][0] = *(const short8*)qr;
    qf[grp][1] = *(const short8*)(qr + 32);
  }

  const f32x4 z4 = {0.f, 0.f, 0.f, 0.f};
  f32x4 oacc[2][4];  // [group][dc]: O^T[d=16dc+4g+r][q]
  #pragma unroll
  for (int grp = 0; grp < 2; ++grp)
    #pragma unroll
    for (int dc = 0; dc < 4; ++dc) oacc[grp][dc] = z4;
  float mrun[2] = {-1e30f, -1e30f};
  float lrun[2] = {0.f, 0.f};
  const int permrow = 8 * (lq >> 2) + (lq & 3);  // K-row perm -> P^T in-lane

  auto tile = [&](int kv0, bool causal) {
    const short* ka = base + (size_t)(kv0 + permrow) * 3072 + 1024 + 8 * g;
    const short8 k0 = *(const short8*)ka;
    const short8 k1 = *(const short8*)(ka + 32);
    const short8 k2 = *(const short8*)(ka + 4 * 3072);
    const short8 k3 = *(const short8*)(ka + 4 * 3072 + 32);
    short8 vf[4];  // V^T[16dc+lq][kv0+8g..+7]
    #pragma unroll
    for (int dc = 0; dc < 4; ++dc)
      vf[dc] = *(const short8*)(vbase + (16 * dc + lq) * 1024 + kv0 + 8 * g);
    #pragma unroll
    for (int grp = 0; grp < 2; ++grp) {
      f32x4 sA = z4, sB = z4;  // S^T: reg r = kv0+8g+r (A) / +4 (B), col q
      __builtin_amdgcn_s_setprio(1);
      sA = MFMA_BF16(k0, qf[grp][0], sA);
      sA = MFMA_BF16(k1, qf[grp][1], sA);
      sB = MFMA_BF16(k2, qf[grp][0], sB);
      sB = MFMA_BF16(k3, qf[grp][1], sB);
      __builtin_amdgcn_s_setprio(0);
      const int q = qw + grp * 16 + lq;
      float mx = -1e30f;
      #pragma unroll
      for (int r = 0; r < 4; ++r) {
        const int colA = kv0 + 8 * g + r, colB = colA + 4;
        float vA = sA[r] * 0.125f, vB = sB[r] * 0.125f;
        const bool okA = causal ? (colA <= q) : (colA < count);
        const bool okB = causal ? (colB <= q) : (colB < count);
        vA = okA ? vA : -1e30f;
        vB = okB ? vB : -1e30f;
        sA[r] = vA; sB[r] = vB;
        mx = fmaxf(mx, fmaxf(vA, vB));
      }
      mx = fmaxf(mx, __shfl_xor(mx, 16, 64));
      mx = fmaxf(mx, __shfl_xor(mx, 32, 64));
      const float mn = fmaxf(mrun[grp], mx);
      const float sf = __expf(mrun[grp] - mn);
      float ps = 0.f;
      #pragma unroll
      for (int r = 0; r < 4; ++r) {
        const float a  = __expf(sA[r] - mn);
        const float c2 = __expf(sB[r] - mn);
        sA[r] = a; sB[r] = c2; ps += a + c2;
      }
      ps += __shfl_xor(ps, 16, 64);
      ps += __shfl_xor(ps, 32, 64);
      lrun[grp] = lrun[grp] * sf + ps;
      mrun[grp] = mn;
      short8 pf;  // P^T B-operand: elem j -> kv = kv0+8g+j, col q
      pf[0] = (short)f2bf(sA[0]); pf[1] = (short)f2bf(sA[1]);
      pf[2] = (short)f2bf(sA[2]); pf[3] = (short)f2bf(sA[3]);
      pf[4] = (short)f2bf(sB[0]); pf[5] = (short)f2bf(sB[1]);
      pf[6] = (short)f2bf(sB[2]); pf[7] = (short)f2bf(sB[3]);
      __builtin_amdgcn_s_setprio(1);
      #pragma unroll
      for (int dc = 0; dc < 4; ++dc) {
        #pragma unroll
        for (int r = 0; r < 4; ++r) oacc[grp][dc][r] *= sf;
        oacc[grp][dc] = MFMA_BF16(vf[dc], pf, oacc[grp][dc]);
      }
      __builtin_amdgcn_s_setprio(0);
    }
  };

  // cond region: cols [0,256) visible iff col < count (count >= 1)
  for (int kv0 = 0; kv0 < 256 && kv0 < count; kv0 += 32) tile(kv0, false);
  // causal region: cols [256, qw+32) visible iff col <= row
  const int kv_end = qw + 32;
  for (int kv0 = 256; kv0 < kv_end; kv0 += 32) tile(kv0, true);

  #pragma unroll
  for (int grp = 0; grp < 2; ++grp) {
    const float inv = 1.0f / lrun[grp];
    unsigned short* yr = y + (size_t)(b * 1024 + qw + grp * 16 + lq) * 1024 + h * 64;
    #pragma unroll
    for (int dc = 0; dc < 4; ++dc)
      #pragma unroll
      for (int r = 0; r < 4; ++r)
        yr[16 * dc + 4 * g + r] = f2bf(oacc[grp][dc][r] * inv);
  }
}

// ---------------- launch ----------------
// Workspace layout (~152.1 MB):
//  [0,16M)   xn bf16 (phase 1) -> vtr bf16 (after QKV GEMM) -> act bf16 [0,64M) (after attn)
//  [16M,64M) qkv bf16
//  [64M,80M) y bf16
//  [80M,112M) x1 fp32
//  [112M,128M) h bf16
//  [128M,134M) WqkvT | [134M,136M) WpT | [136M,144M) W1T | [144M,152M) W2T  (bf16)
//  [152M, +12KB) bqkv fp32 | [152M+16KB, +32B) counts
extern "C" void kernel_launch(void* const* d_in, const int* in_sizes, int n_in,
                              void* d_out, int out_size, void* d_ws, size_t ws_size,
                              hipStream_t stream) {
  (void)in_sizes; (void)n_in; (void)out_size; (void)ws_size;
  const float* x     = (const float*)d_in[0];
  const float* ln1_g = (const float*)d_in[1];
  const float* ln1_b = (const float*)d_in[2];
  const float* Wq    = (const float*)d_in[3];
  const float* bq    = (const float*)d_in[4];
  const float* Wk    = (const float*)d_in[5];
  const float* bk    = (const float*)d_in[6];
  const float* Wv    = (const float*)d_in[7];
  const float* bv    = (const float*)d_in[8];
  const float* Wp    = (const float*)d_in[9];
  const float* bp    = (const float*)d_in[10];
  const float* ln2_g = (const float*)d_in[11];
  const float* ln2_b = (const float*)d_in[12];
  const float* W1    = (const float*)d_in[13];
  const float* b1    = (const float*)d_in[14];
  const float* W2    = (const float*)d_in[15];
  const float* b2    = (const float*)d_in[16];
  const int* cond_mask = (const int*)d_in[17];
  // cond_len=256 / token_len=768 hardcoded (mask simplifies to cond-prefix + causal)

  char* ws = (char*)d_ws;
  const size_t MB = 1u << 20;
  short* xn    = (short*)(ws + 0);
  short* vtr   = (short*)(ws + 0);          // reuses xn region after QKV GEMM
  short* qkv   = (short*)(ws + 16 * MB);
  short* act   = (short*)(ws + 0);          // reuses region after attn
  unsigned short* yb = (unsigned short*)(ws + 64 * MB);
  float* x1    = (float*)(ws + 80 * MB);
  short* hb    = (short*)(ws + 112 * MB);
  short* wqkvT = (short*)(ws + 128 * MB);
  short* wpT   = (short*)(ws + 134 * MB);
  short* w1T   = (short*)(ws + 136 * MB);
  short* w2T   = (short*)(ws + 144 * MB);
  float* bqkv  = (float*)(ws + 152 * MB);
  int* counts  = (int*)(ws + 152 * MB + 16384);

  const dim3 tb(32, 8);
  count_kernel<<<8, 256, 0, stream>>>(cond_mask, counts);
  pack_bias_kernel<<<12, 256, 0, stream>>>(bq, bk, bv, bqkv);
  transpose_kernel<<<dim3(32, 32), tb, 0, stream>>>(Wq, (unsigned short*)wqkvT, 1024, 1024);
  transpose_kernel<<<dim3(32, 32), tb, 0, stream>>>(Wk, (unsigned short*)(wqkvT + 1024 * 1024), 1024, 1024);
  transpose_kernel<<<dim3(32, 32), tb, 0, stream>>>(Wv, (unsigned short*)(wqkvT + 2 * 1024 * 1024), 1024, 1024);
  transpose_kernel<<<dim3(32, 32), tb, 0, stream>>>(Wp, (unsigned short*)wpT, 1024, 1024);
  transpose_kernel<<<dim3(128, 32), tb, 0, stream>>>(W1, (unsigned short*)w1T, 1024, 4096);
  transpose_kernel<<<dim3(32, 128), tb, 0, stream>>>(W2, (unsigned short*)w2T, 4096, 1024);
  ln_kernel<<<8192, 256, 0, stream>>>(x, ln1_g, ln1_b, (unsigned short*)xn);

  gemm_bt_kernel<0><<<dim3(64, 24), 256, 0, stream>>>(xn, wqkvT, bqkv, 3072, 1024,
                                                      (unsigned short*)qkv, nullptr, nullptr);
  vtrans_kernel<<<dim3(32, 2, 128), tb, 0, stream>>>(qkv, vtr);
  attn_kernel<<<dim3(8, 128), 256, 0, stream>>>(qkv, vtr, yb, counts);
  gemm_bt_kernel<2><<<dim3(64, 8), 256, 0, stream>>>((const short*)yb, wpT, bp, 1024, 1024,
                                                     nullptr, x1, x);
  ln_kernel<<<8192, 256, 0, stream>>>(x1, ln2_g, ln2_b, (unsigned short*)hb);
  gemm_bt_kernel<1><<<dim3(64, 32), 256, 0, stream>>>(hb, w1T, b1, 4096, 1024,
                                                      (unsigned short*)act, nullptr, nullptr);
  gemm_bt_kernel<2><<<dim3(64, 8), 256, 0, stream>>>(act, w2T, b2, 1024, 4096,
                                                     nullptr, (float*)d_out, x1);
}

// Round 3
// 498.798 us; speedup vs baseline: 1.0582x; 1.0297x over previous
//
#include <hip/hip_runtime.h>
#include <hip/hip_bf16.h>
#include <cstdint>
#include <cstddef>

// ---------------- types / helpers ----------------
typedef __attribute__((ext_vector_type(8))) short short8;   // 8 x bf16 (4 VGPRs)
typedef __attribute__((ext_vector_type(4))) float f32x4;    // MFMA accumulator
typedef __attribute__((ext_vector_type(4))) unsigned short us4;

#define MFMA_BF16(a, b, c) __builtin_amdgcn_mfma_f32_16x16x32_bf16((a), (b), (c), 0, 0, 0)

__device__ __forceinline__ unsigned short f2bf(float f) {  // fp32 -> bf16 RNE
  unsigned int u = __float_as_uint(f);
  u += 0x7FFFu + ((u >> 16) & 1u);
  return (unsigned short)(u >> 16);
}

#if defined(__has_builtin)
#if __has_builtin(__builtin_amdgcn_global_load_lds)
#define HAVE_GLL 1
#endif
#endif

#ifdef HAVE_GLL
typedef const void __attribute__((address_space(1)))* as1_cvp;
typedef void __attribute__((address_space(3)))* as3_vp;
__device__ __forceinline__ void gll16(const short* g, short* l) {
  // 16B per lane; LDS dest is wave-uniform base + lane*16
  __builtin_amdgcn_global_load_lds((as1_cvp)g, (as3_vp)l, 16, 0, 0);
}
#endif

// ---------------- prep kernels ----------------
__global__ void count_kernel(const int* __restrict__ cm, int* __restrict__ counts) {
  __shared__ int sd[256];
  const int b = blockIdx.x, t = threadIdx.x;
  int s = 0;
  for (int i = t; i < 1024; i += 256) s += cm[b * 1024 + i];
  sd[t] = s; __syncthreads();
  for (int k = 128; k > 0; k >>= 1) { if (t < k) sd[t] += sd[t + k]; __syncthreads(); }
  if (t == 0) counts[b] = sd[0];
}

__global__ void pack_bias_kernel(const float* __restrict__ bq, const float* __restrict__ bk,
                                 const float* __restrict__ bv, float* __restrict__ dst) {
  int i = blockIdx.x * 256 + threadIdx.x;
  dst[i] = (i < 1024) ? bq[i] : (i < 2048 ? bk[i - 1024] : bv[i - 2048]);
}

// src fp32 [R][C] -> dst bf16 [C][R]
__global__ void transpose_kernel(const float* __restrict__ src, unsigned short* __restrict__ dst,
                                 int R, int C) {
  __shared__ float tile[32][33];
  const int c0 = blockIdx.x * 32, r0 = blockIdx.y * 32;
  const int tx = threadIdx.x, ty = threadIdx.y;
  #pragma unroll
  for (int i = ty; i < 32; i += 8)
    tile[i][tx] = src[(size_t)(r0 + i) * C + (c0 + tx)];
  __syncthreads();
  #pragma unroll
  for (int i = ty; i < 32; i += 8)
    dst[(size_t)(c0 + i) * R + (r0 + tx)] = f2bf(tile[tx][i]);
}

// V^T precompute: qkv [B*T][3072] (V at col 2048 + h*64) -> vtr [B*H][64][1024] bf16
__global__ void vtrans_kernel(const short* __restrict__ qkv, short* __restrict__ vtr) {
  __shared__ short tile[32][33];
  const int bh = blockIdx.z;
  const int t0 = blockIdx.x * 32, d0 = blockIdx.y * 32;
  const int b = bh >> 4, h = bh & 15;
  const int tx = threadIdx.x, ty = threadIdx.y;
  const short* src = qkv + (size_t)b * 1024 * 3072 + 2048 + h * 64;
  #pragma unroll
  for (int i = ty; i < 32; i += 8)
    tile[i][tx] = src[(size_t)(t0 + i) * 3072 + d0 + tx];
  __syncthreads();
  short* dst = vtr + (size_t)bh * 65536;
  #pragma unroll
  for (int i = ty; i < 32; i += 8)
    dst[(d0 + i) * 1024 + t0 + tx] = tile[tx][i];
}

// LayerNorm over rows of 1024 fp32 -> bf16
__global__ __launch_bounds__(256) void ln_kernel(const float* __restrict__ in,
                                                 const float* __restrict__ gw,
                                                 const float* __restrict__ bw,
                                                 unsigned short* __restrict__ out) {
  const int row = blockIdx.x, t = threadIdx.x;
  const float4 v = ((const float4*)(in + (size_t)row * 1024))[t];
  float s = v.x + v.y + v.z + v.w;
  float ss = v.x * v.x + v.y * v.y + v.z * v.z + v.w * v.w;
  #pragma unroll
  for (int o = 32; o >= 1; o >>= 1) { s += __shfl_down(s, o, 64); ss += __shfl_down(ss, o, 64); }
  __shared__ float red[8];
  if ((t & 63) == 0) { red[t >> 6] = s; red[4 + (t >> 6)] = ss; }
  __syncthreads();
  const float S  = red[0] + red[1] + red[2] + red[3];
  const float SS = red[4] + red[5] + red[6] + red[7];
  const float mu = S * (1.0f / 1024.0f);
  const float var = SS * (1.0f / 1024.0f) - mu * mu;
  const float rs = rsqrtf(var + 1e-5f);
  const int c = t * 4;
  const float4 g4 = ((const float4*)gw)[t];
  const float4 b4 = ((const float4*)bw)[t];
  us4 o4;
  o4[0] = f2bf((v.x - mu) * rs * g4.x + b4.x);
  o4[1] = f2bf((v.y - mu) * rs * g4.y + b4.y);
  o4[2] = f2bf((v.z - mu) * rs * g4.z + b4.z);
  o4[3] = f2bf((v.w - mu) * rs * g4.w + b4.w);
  *(us4*)(out + (size_t)row * 1024 + c) = o4;
}

// ---------------- GEMM: C[M,N] = A[M,K] (bf16) * BT[N,K]^T (bf16) + bias ----------------
// 128x128 tile, BK=32, 256 threads (4 waves 2x2), 16x16x32 bf16 MFMA.
// EPI 0: out bf16; EPI 1: gelu -> bf16; EPI 2: + res(fp32) -> fp32
template <int EPI>
__global__ __launch_bounds__(256) void gemm_bt_kernel(
    const short* __restrict__ A, const short* __restrict__ BT,
    const float* __restrict__ bias, int N, int K,
    unsigned short* __restrict__ outb, float* __restrict__ outf,
    const float* __restrict__ res) {
  __shared__ alignas(16) short As[4096];
  __shared__ alignas(16) short Bs[4096];
  const int t = threadIdx.x;
  const int l = t & 63, w = t >> 6;
  const int lq = l & 15, g = l >> 4;
  const int wr = w >> 1, wc = w & 1;
  const int bm = blockIdx.x * 128, bn = blockIdx.y * 128;

  const f32x4 z4 = {0.f, 0.f, 0.f, 0.f};
  f32x4 acc[4][4];
  #pragma unroll
  for (int i = 0; i < 4; i++)
    #pragma unroll
    for (int j = 0; j < 4; j++) acc[i][j] = z4;

  const short* ga = A  + (size_t)(bm + (t >> 2)) * K + (t & 3) * 8;
  const short* gb = BT + (size_t)(bn + (t >> 2)) * K + (t & 3) * 8;
  short* lA = As + w * 512;  // wave-uniform LDS base
  short* lB = Bs + w * 512;

  for (int k0 = 0; k0 < K; k0 += 32) {
#ifdef HAVE_GLL
    gll16(ga + k0,                     lA);
    gll16(ga + k0 + (size_t)64 * K,    lA + 2048);
    gll16(gb + k0,                     lB);
    gll16(gb + k0 + (size_t)64 * K,    lB + 2048);
#else
    short8 v0 = *(const short8*)(ga + k0);
    short8 v1 = *(const short8*)(ga + k0 + (size_t)64 * K);
    short8 v2 = *(const short8*)(gb + k0);
    short8 v3 = *(const short8*)(gb + k0 + (size_t)64 * K);
    *(short8*)(As + t * 8) = v0;
    *(short8*)(As + 2048 + t * 8) = v1;
    *(short8*)(Bs + t * 8) = v2;
    *(short8*)(Bs + 2048 + t * 8) = v3;
#endif
    __syncthreads();
    short8 af[4], bfr[4];
    #pragma unroll
    for (int mi = 0; mi < 4; mi++)
      af[mi] = *(const short8*)(As + (wr * 64 + mi * 16 + lq) * 32 + 8 * g);
    #pragma unroll
    for (int ni = 0; ni < 4; ni++)
      bfr[ni] = *(const short8*)(Bs + (wc * 64 + ni * 16 + lq) * 32 + 8 * g);
    #pragma unroll
    for (int mi = 0; mi < 4; mi++)
      #pragma unroll
      for (int ni = 0; ni < 4; ni++)
        acc[mi][ni] = MFMA_BF16(af[mi], bfr[ni], acc[mi][ni]);
    __syncthreads();
  }

  #pragma unroll
  for (int mi = 0; mi < 4; mi++) {
    #pragma unroll
    for (int ni = 0; ni < 4; ni++) {
      const int col = bn + wc * 64 + ni * 16 + lq;
      const float bv = bias[col];
      #pragma unroll
      for (int r = 0; r < 4; r++) {
        const int row = bm + wr * 64 + mi * 16 + 4 * g + r;
        float v = acc[mi][ni][r] + bv;
        const size_t idx = (size_t)row * N + col;
        if (EPI == 1) v = 0.5f * v * (1.0f + erff(v * 0.70710678118654752440f));
        if (EPI == 2) outf[idx] = v + res[idx];
        else          outb[idx] = f2bf(v);
      }
    }
  }
}

// ---------------- flash attention (no LDS/barriers, balanced pairs, prefetch) ----------------
// qkv rows [B*T][3072] = [q|k|v]; vtr [B*H][64][1024] = V^T per (b,h).
// Wave owns q-tiles (p, 63-p) of 16 rows each -> near-constant work per wave.
// Swapped QK^T (S^T = mfma(K,Q)) + permuted K rows so P^T feeds PV B-operand in-lane.
// Softmax in log2 domain (scale = 1/8 * log2e), defer-max THR=8, cvt_pk bf16 pack.
// K/V register double-buffer: tile t+1 loads issued before tile t compute.
__global__ __launch_bounds__(256) void attn_kernel(
    const short* __restrict__ qkv, const short* __restrict__ vtr,
    unsigned short* __restrict__ y, const int* __restrict__ counts) {
  const int bh = blockIdx.y;
  const int b = bh >> 4, h = bh & 15;
  const int t = threadIdx.x, w = t >> 6, l = t & 63;
  const int lq = l & 15, g = l >> 4;
  const int p = blockIdx.x * 4 + w;       // pair index 0..31
  const int qb0 = p * 16, qb1 = (63 - p) * 16;
  const int count = counts[b];

  const short* base  = qkv + (size_t)b * 1024 * 3072 + h * 64;
  const short* vbase = vtr + (size_t)bh * 65536;

  short8 qf[2][2];  // [group][k-half]; B-operand col q = qb[grp]+lq
  {
    const short* qr0 = base + (size_t)(qb0 + lq) * 3072 + 8 * g;
    const short* qr1 = base + (size_t)(qb1 + lq) * 3072 + 8 * g;
    qf[0][0] = *(const short8*)qr0; qf[0][1] = *(const short8*)(qr0 + 32);
    qf[1][0] = *(const short8*)qr1; qf[1][1] = *(const short8*)(qr1 + 32);
  }

  const f32x4 z4 = {0.f, 0.f, 0.f, 0.f};
  f32x4 oacc[2][4];  // [group][dc]: O^T[d=16dc+4g+r][q]
  #pragma unroll
  for (int grp = 0; grp < 2; ++grp)
    #pragma unroll
    for (int dc = 0; dc < 4; ++dc) oacc[grp][dc] = z4;
  float mrun[2] = {-1e30f, -1e30f};
  float lrun[2] = {0.f, 0.f};
  const int permrow = 8 * (lq >> 2) + (lq & 3);  // K-row perm -> P^T in-lane
  const float SC = 0.125f * 1.44269504088896f;   // 1/sqrt(D) * log2(e)

  // tile index space: i < ncond -> kv0 = 32*i ; else kv0 = 256 + 32*(i-ncond)
  const int ncond = min((count + 31) >> 5, 8);
  const int ncausal = (qb1 + 16 - 256 + 31) >> 5;
  const int nt = ncond + ncausal;
  auto kv_of = [&](int i) { return i < ncond ? i * 32 : 256 + (i - ncond) * 32; };

  auto loadt = [&](int kv0, short8 (&kr)[4], short8 (&vr)[4]) {
    const short* ka = base + (size_t)(kv0 + permrow) * 3072 + 1024 + 8 * g;
    kr[0] = *(const short8*)ka;
    kr[1] = *(const short8*)(ka + 32);
    kr[2] = *(const short8*)(ka + 4 * 3072);
    kr[3] = *(const short8*)(ka + 4 * 3072 + 32);
    #pragma unroll
    for (int dc = 0; dc < 4; ++dc)
      vr[dc] = *(const short8*)(vbase + (16 * dc + lq) * 1024 + kv0 + 8 * g);
  };

  auto compute = [&](int i, const short8 (&kr)[4], const short8 (&vr)[4]) {
    const int kv0 = kv_of(i);
    const bool isCond = (i < ncond);
    #pragma unroll
    for (int grp = 0; grp < 2; ++grp) {
      const int qb = grp ? qb1 : qb0;
      if (!isCond && kv0 >= qb + 16) continue;        // group inactive (uniform)
      const bool needMask = isCond ? (kv0 + 32 > count) : (kv0 + 31 > qb);
      f32x4 sA = z4, sB = z4;  // S^T: reg r = kv0+8g+r (A) / +4 (B), col q
      __builtin_amdgcn_s_setprio(1);
      sA = MFMA_BF16(kr[0], qf[grp][0], sA);
      sA = MFMA_BF16(kr[1], qf[grp][1], sA);
      sB = MFMA_BF16(kr[2], qf[grp][0], sB);
      sB = MFMA_BF16(kr[3], qf[grp][1], sB);
      __builtin_amdgcn_s_setprio(0);
      const int q = qb + lq;
      float mx = -1e30f;
      if (needMask) {
        #pragma unroll
        for (int r = 0; r < 4; ++r) {
          const int colA = kv0 + 8 * g + r, colB = colA + 4;
          const bool okA = isCond ? (colA < count) : (colA <= q);
          const bool okB = isCond ? (colB < count) : (colB <= q);
          const float vA = okA ? sA[r] * SC : -1e30f;
          const float vB = okB ? sB[r] * SC : -1e30f;
          sA[r] = vA; sB[r] = vB;
          mx = fmaxf(fmaxf(vA, vB), mx);
        }
      } else {
        #pragma unroll
        for (int r = 0; r < 4; ++r) {
          const float vA = sA[r] * SC, vB = sB[r] * SC;
          sA[r] = vA; sB[r] = vB;
          mx = fmaxf(fmaxf(vA, vB), mx);
        }
      }
      mx = fmaxf(mx, __shfl_xor(mx, 16, 64));
      mx = fmaxf(mx, __shfl_xor(mx, 32, 64));
      float m = mrun[grp];
      if (!__all(mx <= m + 8.0f)) {   // defer-max: rescale only on real growth
        const float mn = fmaxf(m, mx);
        const float sf = exp2f(m - mn);
        lrun[grp] *= sf;
        #pragma unroll
        for (int dc = 0; dc < 4; ++dc)
          #pragma unroll
          for (int r = 0; r < 4; ++r) oacc[grp][dc][r] *= sf;
        mrun[grp] = mn; m = mn;
      }
      float ps = 0.f;
      #pragma unroll
      for (int r = 0; r < 4; ++r) {
        const float a  = exp2f(sA[r] - m);
        const float c2 = exp2f(sB[r] - m);
        sA[r] = a; sB[r] = c2; ps += a + c2;
      }
      ps += __shfl_xor(ps, 16, 64);
      ps += __shfl_xor(ps, 32, 64);
      lrun[grp] += ps;
      union { short8 s8; __hip_bfloat162 h2[4]; } pu;  // P^T: elem j -> kv0+8g+j
      pu.h2[0] = __float22bfloat162_rn(float2{sA[0], sA[1]});
      pu.h2[1] = __float22bfloat162_rn(float2{sA[2], sA[3]});
      pu.h2[2] = __float22bfloat162_rn(float2{sB[0], sB[1]});
      pu.h2[3] = __float22bfloat162_rn(float2{sB[2], sB[3]});
      __builtin_amdgcn_s_setprio(1);
      #pragma unroll
      for (int dc = 0; dc < 4; ++dc)
        oacc[grp][dc] = MFMA_BF16(vr[dc], pu.s8, oacc[grp][dc]);
      __builtin_amdgcn_s_setprio(0);
    }
  };

  // double-buffered K/V register prefetch
  short8 kb0[4], vb0[4], kb1[4], vb1[4];
  loadt(kv_of(0), kb0, vb0);
  for (int i = 0; i < nt; i += 2) {
    if (i + 1 < nt) loadt(kv_of(i + 1), kb1, vb1);
    compute(i, kb0, vb0);
    if (i + 1 >= nt) break;
    if (i + 2 < nt) loadt(kv_of(i + 2), kb0, vb0);
    compute(i + 1, kb1, vb1);
  }

  #pragma unroll
  for (int grp = 0; grp < 2; ++grp) {
    const int qb = grp ? qb1 : qb0;
    const float inv = 1.0f / lrun[grp];
    unsigned short* yr = y + (size_t)(b * 1024 + qb + lq) * 1024 + h * 64;
    #pragma unroll
    for (int dc = 0; dc < 4; ++dc)
      #pragma unroll
      for (int r = 0; r < 4; ++r)
        yr[16 * dc + 4 * g + r] = f2bf(oacc[grp][dc][r] * inv);
  }
}

// ---------------- launch ----------------
// Workspace layout (~152.1 MB):
//  [0,16M)   xn bf16 (phase 1) -> vtr bf16 (after QKV GEMM) -> act bf16 [0,64M) (after attn)
//  [16M,64M) qkv bf16
//  [64M,80M) y bf16
//  [80M,112M) x1 fp32
//  [112M,128M) h bf16
//  [128M,134M) WqkvT | [134M,136M) WpT | [136M,144M) W1T | [144M,152M) W2T  (bf16)
//  [152M, +12KB) bqkv fp32 | [152M+16KB, +32B) counts
extern "C" void kernel_launch(void* const* d_in, const int* in_sizes, int n_in,
                              void* d_out, int out_size, void* d_ws, size_t ws_size,
                              hipStream_t stream) {
  (void)in_sizes; (void)n_in; (void)out_size; (void)ws_size;
  const float* x     = (const float*)d_in[0];
  const float* ln1_g = (const float*)d_in[1];
  const float* ln1_b = (const float*)d_in[2];
  const float* Wq    = (const float*)d_in[3];
  const float* bq    = (const float*)d_in[4];
  const float* Wk    = (const float*)d_in[5];
  const float* bk    = (const float*)d_in[6];
  const float* Wv    = (const float*)d_in[7];
  const float* bv    = (const float*)d_in[8];
  const float* Wp    = (const float*)d_in[9];
  const float* bp    = (const float*)d_in[10];
  const float* ln2_g = (const float*)d_in[11];
  const float* ln2_b = (const float*)d_in[12];
  const float* W1    = (const float*)d_in[13];
  const float* b1    = (const float*)d_in[14];
  const float* W2    = (const float*)d_in[15];
  const float* b2    = (const float*)d_in[16];
  const int* cond_mask = (const int*)d_in[17];
  // cond_len=256 / token_len=768 hardcoded (mask simplifies to cond-prefix + causal)

  char* ws = (char*)d_ws;
  const size_t MB = 1u << 20;
  short* xn    = (short*)(ws + 0);
  short* vtr   = (short*)(ws + 0);          // reuses xn region after QKV GEMM
  short* qkv   = (short*)(ws + 16 * MB);
  short* act   = (short*)(ws + 0);          // reuses region after attn
  unsigned short* yb = (unsigned short*)(ws + 64 * MB);
  float* x1    = (float*)(ws + 80 * MB);
  short* hb    = (short*)(ws + 112 * MB);
  short* wqkvT = (short*)(ws + 128 * MB);
  short* wpT   = (short*)(ws + 134 * MB);
  short* w1T   = (short*)(ws + 136 * MB);
  short* w2T   = (short*)(ws + 144 * MB);
  float* bqkv  = (float*)(ws + 152 * MB);
  int* counts  = (int*)(ws + 152 * MB + 16384);

  const dim3 tb(32, 8);
  count_kernel<<<8, 256, 0, stream>>>(cond_mask, counts);
  pack_bias_kernel<<<12, 256, 0, stream>>>(bq, bk, bv, bqkv);
  transpose_kernel<<<dim3(32, 32), tb, 0, stream>>>(Wq, (unsigned short*)wqkvT, 1024, 1024);
  transpose_kernel<<<dim3(32, 32), tb, 0, stream>>>(Wk, (unsigned short*)(wqkvT + 1024 * 1024), 1024, 1024);
  transpose_kernel<<<dim3(32, 32), tb, 0, stream>>>(Wv, (unsigned short*)(wqkvT + 2 * 1024 * 1024), 1024, 1024);
  transpose_kernel<<<dim3(32, 32), tb, 0, stream>>>(Wp, (unsigned short*)wpT, 1024, 1024);
  transpose_kernel<<<dim3(128, 32), tb, 0, stream>>>(W1, (unsigned short*)w1T, 1024, 4096);
  transpose_kernel<<<dim3(32, 128), tb, 0, stream>>>(W2, (unsigned short*)w2T, 4096, 1024);
  ln_kernel<<<8192, 256, 0, stream>>>(x, ln1_g, ln1_b, (unsigned short*)xn);

  gemm_bt_kernel<0><<<dim3(64, 24), 256, 0, stream>>>(xn, wqkvT, bqkv, 3072, 1024,
                                                      (unsigned short*)qkv, nullptr, nullptr);
  vtrans_kernel<<<dim3(32, 2, 128), tb, 0, stream>>>(qkv, vtr);
  attn_kernel<<<dim3(8, 128), 256, 0, stream>>>(qkv, vtr, yb, counts);
  gemm_bt_kernel<2><<<dim3(64, 8), 256, 0, stream>>>((const short*)yb, wpT, bp, 1024, 1024,
                                                     nullptr, x1, x);
  ln_kernel<<<8192, 256, 0, stream>>>(x1, ln2_g, ln2_b, (unsigned short*)hb);
  gemm_bt_kernel<1><<<dim3(64, 32), 256, 0, stream>>>(hb, w1T, b1, 4096, 1024,
                                                      (unsigned short*)act, nullptr, nullptr);
  gemm_bt_kernel<2><<<dim3(64, 8), 256, 0, stream>>>(act, w2T, b2, 1024, 4096,
                                                     nullptr, (float*)d_out, x1);
}

// Round 5
// 486.884 us; speedup vs baseline: 1.0841x; 1.0245x over previous
//
#include <hip/hip_runtime.h>
#include <hip/hip_bf16.h>
#include <cstdint>
#include <cstddef>

// ---------------- types / helpers ----------------
typedef __attribute__((ext_vector_type(8))) short short8;   // 8 x bf16 (4 VGPRs)
typedef __attribute__((ext_vector_type(4))) float f32x4;    // MFMA accumulator
typedef __attribute__((ext_vector_type(4))) unsigned short us4;

#define MFMA_BF16(a, b, c) __builtin_amdgcn_mfma_f32_16x16x32_bf16((a), (b), (c), 0, 0, 0)
#define VMCNT(n) asm volatile("s_waitcnt vmcnt(" #n ")" ::: "memory")

__device__ __forceinline__ unsigned short f2bf(float f) {  // fp32 -> bf16 RNE
  unsigned int u = __float_as_uint(f);
  u += 0x7FFFu + ((u >> 16) & 1u);
  return (unsigned short)(u >> 16);
}

typedef const void __attribute__((address_space(1)))* as1_cvp;
typedef void __attribute__((address_space(3)))* as3_vp;
// Always declared (host pass parses device fns); body device-only.
__device__ __forceinline__ void gll16(const short* g, short* l) {
#if defined(__HIP_DEVICE_COMPILE__)
  __builtin_amdgcn_global_load_lds((as1_cvp)g, (as3_vp)l, 16, 0, 0);
#else
  (void)g; (void)l;
#endif
}

// ---------------- prep kernels ----------------
__global__ void count_kernel(const int* __restrict__ cm, int* __restrict__ counts) {
  __shared__ int sd[256];
  const int b = blockIdx.x, t = threadIdx.x;
  int s = 0;
  for (int i = t; i < 1024; i += 256) s += cm[b * 1024 + i];
  sd[t] = s; __syncthreads();
  for (int k = 128; k > 0; k >>= 1) { if (t < k) sd[t] += sd[t + k]; __syncthreads(); }
  if (t == 0) counts[b] = sd[0];
}

__global__ void pack_bias_kernel(const float* __restrict__ bq, const float* __restrict__ bk,
                                 const float* __restrict__ bv, float* __restrict__ dst) {
  int i = blockIdx.x * 256 + threadIdx.x;
  dst[i] = (i < 1024) ? bq[i] : (i < 2048 ? bk[i - 1024] : bv[i - 2048]);
}

// src fp32 [R][C] -> dst bf16 [C][R]
__global__ void transpose_kernel(const float* __restrict__ src, unsigned short* __restrict__ dst,
                                 int R, int C) {
  __shared__ float tile[32][33];
  const int c0 = blockIdx.x * 32, r0 = blockIdx.y * 32;
  const int tx = threadIdx.x, ty = threadIdx.y;
  #pragma unroll
  for (int i = ty; i < 32; i += 8)
    tile[i][tx] = src[(size_t)(r0 + i) * C + (c0 + tx)];
  __syncthreads();
  #pragma unroll
  for (int i = ty; i < 32; i += 8)
    dst[(size_t)(c0 + i) * R + (r0 + tx)] = f2bf(tile[tx][i]);
}

// V^T precompute: qkv [B*T][3072] (V at col 2048 + h*64) -> vtr [B*H][64][1024] bf16
__global__ void vtrans_kernel(const short* __restrict__ qkv, short* __restrict__ vtr) {
  __shared__ short tile[32][33];
  const int bh = blockIdx.z;
  const int t0 = blockIdx.x * 32, d0 = blockIdx.y * 32;
  const int b = bh >> 4, h = bh & 15;
  const int tx = threadIdx.x, ty = threadIdx.y;
  const short* src = qkv + (size_t)b * 1024 * 3072 + 2048 + h * 64;
  #pragma unroll
  for (int i = ty; i < 32; i += 8)
    tile[i][tx] = src[(size_t)(t0 + i) * 3072 + d0 + tx];
  __syncthreads();
  short* dst = vtr + (size_t)bh * 65536;
  #pragma unroll
  for (int i = ty; i < 32; i += 8)
    dst[(d0 + i) * 1024 + t0 + tx] = tile[tx][i];
}

// LayerNorm over rows of 1024 fp32 -> bf16
__global__ __launch_bounds__(256) void ln_kernel(const float* __restrict__ in,
                                                 const float* __restrict__ gw,
                                                 const float* __restrict__ bw,
                                                 unsigned short* __restrict__ out) {
  const int row = blockIdx.x, t = threadIdx.x;
  const float4 v = ((const float4*)(in + (size_t)row * 1024))[t];
  float s = v.x + v.y + v.z + v.w;
  float ss = v.x * v.x + v.y * v.y + v.z * v.z + v.w * v.w;
  #pragma unroll
  for (int o = 32; o >= 1; o >>= 1) { s += __shfl_down(s, o, 64); ss += __shfl_down(ss, o, 64); }
  __shared__ float red[8];
  if ((t & 63) == 0) { red[t >> 6] = s; red[4 + (t >> 6)] = ss; }
  __syncthreads();
  const float S  = red[0] + red[1] + red[2] + red[3];
  const float SS = red[4] + red[5] + red[6] + red[7];
  const float mu = S * (1.0f / 1024.0f);
  const float var = SS * (1.0f / 1024.0f) - mu * mu;
  const float rs = rsqrtf(var + 1e-5f);
  const int c = t * 4;
  const float4 g4 = ((const float4*)gw)[t];
  const float4 b4 = ((const float4*)bw)[t];
  us4 o4;
  o4[0] = f2bf((v.x - mu) * rs * g4.x + b4.x);
  o4[1] = f2bf((v.y - mu) * rs * g4.y + b4.y);
  o4[2] = f2bf((v.z - mu) * rs * g4.z + b4.z);
  o4[3] = f2bf((v.w - mu) * rs * g4.w + b4.w);
  *(us4*)(out + (size_t)row * 1024 + c) = o4;
}

// ---------------- GEMM 128x128 (2-phase, legacy) for fp32-out epilogues ----------------
// EPI 2: + res(fp32) -> fp32
template <int EPI>
__global__ __launch_bounds__(256) void gemm_bt_kernel(
    const short* __restrict__ A, const short* __restrict__ BT,
    const float* __restrict__ bias, int N, int K,
    unsigned short* __restrict__ outb, float* __restrict__ outf,
    const float* __restrict__ res) {
  __shared__ alignas(16) short As[4096];
  __shared__ alignas(16) short Bs[4096];
  const int t = threadIdx.x;
  const int l = t & 63, w = t >> 6;
  const int lq = l & 15, g = l >> 4;
  const int wr = w >> 1, wc = w & 1;
  const int bm = blockIdx.x * 128, bn = blockIdx.y * 128;

  const f32x4 z4 = {0.f, 0.f, 0.f, 0.f};
  f32x4 acc[4][4];
  #pragma unroll
  for (int i = 0; i < 4; i++)
    #pragma unroll
    for (int j = 0; j < 4; j++) acc[i][j] = z4;

  const short* ga = A  + (size_t)(bm + (t >> 2)) * K + (t & 3) * 8;
  const short* gb = BT + (size_t)(bn + (t >> 2)) * K + (t & 3) * 8;
  short* lA = As + w * 512;
  short* lB = Bs + w * 512;

  for (int k0 = 0; k0 < K; k0 += 32) {
    gll16(ga + k0,                  lA);
    gll16(ga + k0 + (size_t)64 * K, lA + 2048);
    gll16(gb + k0,                  lB);
    gll16(gb + k0 + (size_t)64 * K, lB + 2048);
    __syncthreads();
    short8 af[4], bfr[4];
    #pragma unroll
    for (int mi = 0; mi < 4; mi++)
      af[mi] = *(const short8*)(As + (wr * 64 + mi * 16 + lq) * 32 + 8 * g);
    #pragma unroll
    for (int ni = 0; ni < 4; ni++)
      bfr[ni] = *(const short8*)(Bs + (wc * 64 + ni * 16 + lq) * 32 + 8 * g);
    #pragma unroll
    for (int mi = 0; mi < 4; mi++)
      #pragma unroll
      for (int ni = 0; ni < 4; ni++)
        acc[mi][ni] = MFMA_BF16(af[mi], bfr[ni], acc[mi][ni]);
    __syncthreads();
  }

  #pragma unroll
  for (int mi = 0; mi < 4; mi++) {
    #pragma unroll
    for (int ni = 0; ni < 4; ni++) {
      const int col = bn + wc * 64 + ni * 16 + lq;
      const float bv = bias[col];
      #pragma unroll
      for (int r = 0; r < 4; r++) {
        const int row = bm + wr * 64 + mi * 16 + 4 * g + r;
        float v = acc[mi][ni][r] + bv;
        const size_t idx = (size_t)row * N + col;
        if (EPI == 1) v = 0.5f * v * (1.0f + erff(v * 0.70710678118654752440f));
        if (EPI == 2) outf[idx] = v + res[idx];
        else          outb[idx] = f2bf(v);
      }
    }
  }
}

// ---------------- GEMM 256x256, 8-phase, counted vmcnt (T3+T4), swizzled LDS (T2), setprio (T5) ----
// C[M,N] = A[M,K]*BT[N,K]^T + bias. EPI 0: ->bf16, EPI 1: gelu->bf16.
// 512 threads = 8 waves (2M x 4N), per-wave 128x64 output, BK=64, LDS 128KB (2 bufs).
// Stage order/iter v: Ah1(v+1), Bh1(v+1), Ah0(v+2), Bh0(v+2). vmcnt(6)@ph1, vmcnt(8)@ph4.
// Swizzle: 16B-unit ^= (row&7), applied to global SOURCE col at stage + to ds_read addr.
template <int EPI>
__global__ __launch_bounds__(512, 2) void gemm256_kernel(
    const short* __restrict__ A, const short* __restrict__ BT,
    const float* __restrict__ bias, int N, int K,
    unsigned short* __restrict__ outb) {
  __shared__ alignas(16) short lds[65536];  // [buf:32768][A/B:16384][half:8192] shorts
  const int t = threadIdx.x;
  const int l = t & 63, w = t >> 6;
  const int lq = l & 15, g = l >> 4;
  const int wr = w >> 2, wc = w & 3;
  const int bm = blockIdx.x * 256, bn = blockIdx.y * 256;
  const int NT = K >> 6;

  const int csw = ((t & 7) ^ ((t >> 3) & 7)) * 8;   // pre-swizzled global k-offset (shorts)
  const int sA = t >> 3;                             // 0..63
  const int sB = ((t >> 8) & 1) * 64 + ((t >> 3) & 31);

  const f32x4 z4 = {0.f, 0.f, 0.f, 0.f};
  f32x4 acc[8][4];
  #pragma unroll
  for (int i = 0; i < 8; i++)
    #pragma unroll
    for (int j = 0; j < 4; j++) acc[i][j] = z4;

  auto stageA = [&](int buf, int h, int k0) {
    const short* src = A + (size_t)(bm + h * 64 + sA) * K + k0 + csw;
    short* dst = lds + buf * 32768 + h * 8192 + t * 8;
    gll16(src, dst);
    gll16(src + (size_t)128 * K, dst + 4096);
  };
  auto stageB = [&](int buf, int h, int k0) {
    const short* src = BT + (size_t)(bn + h * 32 + sB) * K + k0 + csw;
    short* dst = lds + buf * 32768 + 16384 + h * 8192 + t * 8;
    gll16(src, dst);
    gll16(src + (size_t)128 * K, dst + 4096);
  };
  auto rdA = [&](int buf, int mh, int mi2, int kk) {
    const int ra = wr * 64 + mi2 * 16 + lq;
    const int unit = (kk * 4 + g) ^ (ra & 7);
    return *(const short8*)(lds + buf * 32768 + mh * 8192 + ra * 64 + unit * 8);
  };
  auto rdB = [&](int buf, int nh, int ni2, int kk) {
    const int rb = wc * 32 + ni2 * 16 + lq;
    const int unit = (kk * 4 + g) ^ (rb & 7);
    return *(const short8*)(lds + buf * 32768 + 16384 + nh * 8192 + rb * 64 + unit * 8);
  };

  // prologue: Ah0(0) Bh0(0) Ah1(0) Bh1(0) Ah0(1) Bh0(1); wait oldest 2 halves.
  stageA(0, 0, 0);  stageB(0, 0, 0);
  stageA(0, 1, 0);  stageB(0, 1, 0);
  stageA(1, 0, 64); stageB(1, 0, 64);
  VMCNT(8);
  __builtin_amdgcn_s_barrier();

  short8 a[4][2], b0[2][2], b1[2][2];
  for (int v = 0; v < NT; ++v) {
    const int cur = v & 1, nxt = cur ^ 1;
    // ---- ph1: quad (0,0) ----
    #pragma unroll
    for (int mi2 = 0; mi2 < 4; ++mi2)
      #pragma unroll
      for (int kk = 0; kk < 2; ++kk) a[mi2][kk] = rdA(cur, 0, mi2, kk);
    #pragma unroll
    for (int ni2 = 0; ni2 < 2; ++ni2)
      #pragma unroll
      for (int kk = 0; kk < 2; ++kk) b0[ni2][kk] = rdB(cur, 0, ni2, kk);
    if (v + 1 < NT) stageA(nxt, 1, (v + 1) * 64);
    if (v + 1 < NT) { VMCNT(6); } else { VMCNT(0); }
    __builtin_amdgcn_s_barrier();
    __builtin_amdgcn_s_setprio(1);
    #pragma unroll
    for (int mi2 = 0; mi2 < 4; ++mi2)
      #pragma unroll
      for (int ni2 = 0; ni2 < 2; ++ni2)
        #pragma unroll
        for (int kk = 0; kk < 2; ++kk)
          acc[mi2][ni2] = MFMA_BF16(a[mi2][kk], b0[ni2][kk], acc[mi2][ni2]);
    __builtin_amdgcn_s_setprio(0);
    __builtin_amdgcn_s_barrier();
    // ---- ph2: quad (0,1) ----
    #pragma unroll
    for (int ni2 = 0; ni2 < 2; ++ni2)
      #pragma unroll
      for (int kk = 0; kk < 2; ++kk) b1[ni2][kk] = rdB(cur, 1, ni2, kk);
    if (v + 1 < NT) stageB(nxt, 1, (v + 1) * 64);
    __builtin_amdgcn_s_barrier();
    __builtin_amdgcn_s_setprio(1);
    #pragma unroll
    for (int mi2 = 0; mi2 < 4; ++mi2)
      #pragma unroll
      for (int ni2 = 0; ni2 < 2; ++ni2)
        #pragma unroll
        for (int kk = 0; kk < 2; ++kk)
          acc[mi2][2 + ni2] = MFMA_BF16(a[mi2][kk], b1[ni2][kk], acc[mi2][2 + ni2]);
    __builtin_amdgcn_s_setprio(0);
    __builtin_amdgcn_s_barrier();
    // ---- ph3: quad (1,0) ----
    #pragma unroll
    for (int mi2 = 0; mi2 < 4; ++mi2)
      #pragma unroll
      for (int kk = 0; kk < 2; ++kk) a[mi2][kk] = rdA(cur, 1, mi2, kk);
    if (v + 2 < NT) stageA(cur, 0, (v + 2) * 64);
    __builtin_amdgcn_s_barrier();
    __builtin_amdgcn_s_setprio(1);
    #pragma unroll
    for (int mi2 = 0; mi2 < 4; ++mi2)
      #pragma unroll
      for (int ni2 = 0; ni2 < 2; ++ni2)
        #pragma unroll
        for (int kk = 0; kk < 2; ++kk)
          acc[4 + mi2][ni2] = MFMA_BF16(a[mi2][kk], b0[ni2][kk], acc[4 + mi2][ni2]);
    __builtin_amdgcn_s_setprio(0);
    __builtin_amdgcn_s_barrier();
    // ---- ph4: quad (1,1) ----
    if (v + 2 < NT) stageB(cur, 0, (v + 2) * 64);
    if (v + 1 < NT) {
      if (v + 2 < NT) { VMCNT(8); } else { VMCNT(4); }
    }
    __builtin_amdgcn_s_barrier();
    __builtin_amdgcn_s_setprio(1);
    #pragma unroll
    for (int mi2 = 0; mi2 < 4; ++mi2)
      #pragma unroll
      for (int ni2 = 0; ni2 < 2; ++ni2)
        #pragma unroll
        for (int kk = 0; kk < 2; ++kk)
          acc[4 + mi2][2 + ni2] = MFMA_BF16(a[mi2][kk], b1[ni2][kk], acc[4 + mi2][2 + ni2]);
    __builtin_amdgcn_s_setprio(0);
    __builtin_amdgcn_s_barrier();
  }

  // epilogue: bias(+gelu) -> LDS bf16 [256][256] -> coalesced dwordx4 stores
  unsigned short* eb = (unsigned short*)lds;
  #pragma unroll
  for (int mi = 0; mi < 8; ++mi) {
    #pragma unroll
    for (int ni = 0; ni < 4; ++ni) {
      const int col = wc * 64 + (ni >> 1) * 32 + (ni & 1) * 16 + lq;
      const float bv = bias[bn + col];
      #pragma unroll
      for (int r = 0; r < 4; ++r) {
        const int row = wr * 128 + (mi >> 2) * 64 + (mi & 3) * 16 + 4 * g + r;
        float vv = acc[mi][ni][r] + bv;
        if (EPI == 1) vv = 0.5f * vv * (1.0f + erff(vv * 0.70710678118654752440f));
        eb[row * 256 + col] = f2bf(vv);
      }
    }
  }
  __syncthreads();
  #pragma unroll
  for (int it = 0; it < 16; ++it) {
    const int unit = it * 512 + t;          // 16B units over 128KB
    const int row = unit >> 5, c8 = unit & 31;
    const short8 vv = *(const short8*)(lds + unit * 8);
    *(short8*)((short*)outb + (size_t)(bm + row) * N + bn + c8 * 8) = vv;
  }
}

// ---------------- flash attention (unchanged) ----------------
__global__ __launch_bounds__(256) void attn_kernel(
    const short* __restrict__ qkv, const short* __restrict__ vtr,
    unsigned short* __restrict__ y, const int* __restrict__ counts) {
  const int bh = blockIdx.y;
  const int b = bh >> 4, h = bh & 15;
  const int t = threadIdx.x, w = t >> 6, l = t & 63;
  const int lq = l & 15, g = l >> 4;
  const int p = blockIdx.x * 4 + w;
  const int qb0 = p * 16, qb1 = (63 - p) * 16;
  const int count = counts[b];

  const short* base  = qkv + (size_t)b * 1024 * 3072 + h * 64;
  const short* vbase = vtr + (size_t)bh * 65536;

  short8 qf[2][2];
  {
    const short* qr0 = base + (size_t)(qb0 + lq) * 3072 + 8 * g;
    const short* qr1 = base + (size_t)(qb1 + lq) * 3072 + 8 * g;
    qf[0][0] = *(const short8*)qr0; qf[0][1] = *(const short8*)(qr0 + 32);
    qf[1][0] = *(const short8*)qr1; qf[1][1] = *(const short8*)(qr1 + 32);
  }

  const f32x4 z4 = {0.f, 0.f, 0.f, 0.f};
  f32x4 oacc[2][4];
  #pragma unroll
  for (int grp = 0; grp < 2; ++grp)
    #pragma unroll
    for (int dc = 0; dc < 4; ++dc) oacc[grp][dc] = z4;
  float mrun[2] = {-1e30f, -1e30f};
  float lrun[2] = {0.f, 0.f};
  const int permrow = 8 * (lq >> 2) + (lq & 3);
  const float SC = 0.125f * 1.44269504088896f;

  const int ncond = min((count + 31) >> 5, 8);
  const int ncausal = (qb1 + 16 - 256 + 31) >> 5;
  const int nt = ncond + ncausal;
  auto kv_of = [&](int i) { return i < ncond ? i * 32 : 256 + (i - ncond) * 32; };

  auto loadt = [&](int kv0, short8 (&kr)[4], short8 (&vr)[4]) {
    const short* ka = base + (size_t)(kv0 + permrow) * 3072 + 1024 + 8 * g;
    kr[0] = *(const short8*)ka;
    kr[1] = *(const short8*)(ka + 32);
    kr[2] = *(const short8*)(ka + 4 * 3072);
    kr[3] = *(const short8*)(ka + 4 * 3072 + 32);
    #pragma unroll
    for (int dc = 0; dc < 4; ++dc)
      vr[dc] = *(const short8*)(vbase + (16 * dc + lq) * 1024 + kv0 + 8 * g);
  };

  auto compute = [&](int i, const short8 (&kr)[4], const short8 (&vr)[4]) {
    const int kv0 = kv_of(i);
    const bool isCond = (i < ncond);
    #pragma unroll
    for (int grp = 0; grp < 2; ++grp) {
      const int qb = grp ? qb1 : qb0;
      if (!isCond && kv0 >= qb + 16) continue;
      const bool needMask = isCond ? (kv0 + 32 > count) : (kv0 + 31 > qb);
      f32x4 sA = z4, sB = z4;
      __builtin_amdgcn_s_setprio(1);
      sA = MFMA_BF16(kr[0], qf[grp][0], sA);
      sA = MFMA_BF16(kr[1], qf[grp][1], sA);
      sB = MFMA_BF16(kr[2], qf[grp][0], sB);
      sB = MFMA_BF16(kr[3], qf[grp][1], sB);
      __builtin_amdgcn_s_setprio(0);
      const int q = qb + lq;
      float mx = -1e30f;
      if (needMask) {
        #pragma unroll
        for (int r = 0; r < 4; ++r) {
          const int colA = kv0 + 8 * g + r, colB = colA + 4;
          const bool okA = isCond ? (colA < count) : (colA <= q);
          const bool okB = isCond ? (colB < count) : (colB <= q);
          const float vA = okA ? sA[r] * SC : -1e30f;
          const float vB = okB ? sB[r] * SC : -1e30f;
          sA[r] = vA; sB[r] = vB;
          mx = fmaxf(fmaxf(vA, vB), mx);
        }
      } else {
        #pragma unroll
        for (int r = 0; r < 4; ++r) {
          const float vA = sA[r] * SC, vB = sB[r] * SC;
          sA[r] = vA; sB[r] = vB;
          mx = fmaxf(fmaxf(vA, vB), mx);
        }
      }
      mx = fmaxf(mx, __shfl_xor(mx, 16, 64));
      mx = fmaxf(mx, __shfl_xor(mx, 32, 64));
      float m = mrun[grp];
      if (!__all(mx <= m + 8.0f)) {
        const float mn = fmaxf(m, mx);
        const float sf = exp2f(m - mn);
        lrun[grp] *= sf;
        #pragma unroll
        for (int dc = 0; dc < 4; ++dc)
          #pragma unroll
          for (int r = 0; r < 4; ++r) oacc[grp][dc][r] *= sf;
        mrun[grp] = mn; m = mn;
      }
      float ps = 0.f;
      #pragma unroll
      for (int r = 0; r < 4; ++r) {
        const float aa = exp2f(sA[r] - m);
        const float c2 = exp2f(sB[r] - m);
        sA[r] = aa; sB[r] = c2; ps += aa + c2;
      }
      ps += __shfl_xor(ps, 16, 64);
      ps += __shfl_xor(ps, 32, 64);
      lrun[grp] += ps;
      union { short8 s8; __hip_bfloat162 h2[4]; } pu;
      pu.h2[0] = __float22bfloat162_rn(float2{sA[0], sA[1]});
      pu.h2[1] = __float22bfloat162_rn(float2{sA[2], sA[3]});
      pu.h2[2] = __float22bfloat162_rn(float2{sB[0], sB[1]});
      pu.h2[3] = __float22bfloat162_rn(float2{sB[2], sB[3]});
      __builtin_amdgcn_s_setprio(1);
      #pragma unroll
      for (int dc = 0; dc < 4; ++dc)
        oacc[grp][dc] = MFMA_BF16(vr[dc], pu.s8, oacc[grp][dc]);
      __builtin_amdgcn_s_setprio(0);
    }
  };

  short8 kb0[4], vb0[4], kb1[4], vb1[4];
  loadt(kv_of(0), kb0, vb0);
  for (int i = 0; i < nt; i += 2) {
    if (i + 1 < nt) loadt(kv_of(i + 1), kb1, vb1);
    compute(i, kb0, vb0);
    if (i + 1 >= nt) break;
    if (i + 2 < nt) loadt(kv_of(i + 2), kb0, vb0);
    compute(i + 1, kb1, vb1);
  }

  #pragma unroll
  for (int grp = 0; grp < 2; ++grp) {
    const int qb = grp ? qb1 : qb0;
    const float inv = 1.0f / lrun[grp];
    unsigned short* yr = y + (size_t)(b * 1024 + qb + lq) * 1024 + h * 64;
    #pragma unroll
    for (int dc = 0; dc < 4; ++dc)
      #pragma unroll
      for (int r = 0; r < 4; ++r)
        yr[16 * dc + 4 * g + r] = f2bf(oacc[grp][dc][r] * inv);
  }
}

// ---------------- launch ----------------
extern "C" void kernel_launch(void* const* d_in, const int* in_sizes, int n_in,
                              void* d_out, int out_size, void* d_ws, size_t ws_size,
                              hipStream_t stream) {
  (void)in_sizes; (void)n_in; (void)out_size; (void)ws_size;
  const float* x     = (const float*)d_in[0];
  const float* ln1_g = (const float*)d_in[1];
  const float* ln1_b = (const float*)d_in[2];
  const float* Wq    = (const float*)d_in[3];
  const float* bq    = (const float*)d_in[4];
  const float* Wk    = (const float*)d_in[5];
  const float* bk    = (const float*)d_in[6];
  const float* Wv    = (const float*)d_in[7];
  const float* bv    = (const float*)d_in[8];
  const float* Wp    = (const float*)d_in[9];
  const float* bp    = (const float*)d_in[10];
  const float* ln2_g = (const float*)d_in[11];
  const float* ln2_b = (const float*)d_in[12];
  const float* W1    = (const float*)d_in[13];
  const float* b1    = (const float*)d_in[14];
  const float* W2    = (const float*)d_in[15];
  const float* b2    = (const float*)d_in[16];
  const int* cond_mask = (const int*)d_in[17];

  char* ws = (char*)d_ws;
  const size_t MB = 1u << 20;
  short* xn    = (short*)(ws + 0);
  short* vtr   = (short*)(ws + 0);
  short* qkv   = (short*)(ws + 16 * MB);
  short* act   = (short*)(ws + 0);
  unsigned short* yb = (unsigned short*)(ws + 64 * MB);
  float* x1    = (float*)(ws + 80 * MB);
  short* hb    = (short*)(ws + 112 * MB);
  short* wqkvT = (short*)(ws + 128 * MB);
  short* wpT   = (short*)(ws + 134 * MB);
  short* w1T   = (short*)(ws + 136 * MB);
  short* w2T   = (short*)(ws + 144 * MB);
  float* bqkv  = (float*)(ws + 152 * MB);
  int* counts  = (int*)(ws + 152 * MB + 16384);

  const dim3 tb(32, 8);
  count_kernel<<<8, 256, 0, stream>>>(cond_mask, counts);
  pack_bias_kernel<<<12, 256, 0, stream>>>(bq, bk, bv, bqkv);
  transpose_kernel<<<dim3(32, 32), tb, 0, stream>>>(Wq, (unsigned short*)wqkvT, 1024, 1024);
  transpose_kernel<<<dim3(32, 32), tb, 0, stream>>>(Wk, (unsigned short*)(wqkvT + 1024 * 1024), 1024, 1024);
  transpose_kernel<<<dim3(32, 32), tb, 0, stream>>>(Wv, (unsigned short*)(wqkvT + 2 * 1024 * 1024), 1024, 1024);
  transpose_kernel<<<dim3(32, 32), tb, 0, stream>>>(Wp, (unsigned short*)wpT, 1024, 1024);
  transpose_kernel<<<dim3(128, 32), tb, 0, stream>>>(W1, (unsigned short*)w1T, 1024, 4096);
  transpose_kernel<<<dim3(32, 128), tb, 0, stream>>>(W2, (unsigned short*)w2T, 4096, 1024);
  ln_kernel<<<8192, 256, 0, stream>>>(x, ln1_g, ln1_b, (unsigned short*)xn);

  gemm256_kernel<0><<<dim3(32, 12), 512, 0, stream>>>(xn, wqkvT, bqkv, 3072, 1024,
                                                      (unsigned short*)qkv);
  vtrans_kernel<<<dim3(32, 2, 128), tb, 0, stream>>>(qkv, vtr);
  attn_kernel<<<dim3(8, 128), 256, 0, stream>>>(qkv, vtr, yb, counts);
  gemm_bt_kernel<2><<<dim3(64, 8), 256, 0, stream>>>((const short*)yb, wpT, bp, 1024, 1024,
                                                     nullptr, x1, x);
  ln_kernel<<<8192, 256, 0, stream>>>(x1, ln2_g, ln2_b, (unsigned short*)hb);
  gemm256_kernel<1><<<dim3(32, 16), 512, 0, stream>>>(hb, w1T, b1, 4096, 1024,
                                                      (unsigned short*)act);
  gemm_bt_kernel<2><<<dim3(64, 8), 256, 0, stream>>>(act, w2T, b2, 1024, 4096,
                                                     nullptr, (float*)d_out, x1);
}

// Round 6
// 468.356 us; speedup vs baseline: 1.1270x; 1.0396x over previous
//
#include <hip/hip_runtime.h>
#include <hip/hip_bf16.h>
#include <cstdint>
#include <cstddef>

// ---------------- types / helpers ----------------
typedef __attribute__((ext_vector_type(8))) short short8;   // 8 x bf16 (4 VGPRs)
typedef __attribute__((ext_vector_type(4))) float f32x4;    // MFMA accumulator
typedef __attribute__((ext_vector_type(4))) unsigned short us4;

#define MFMA_BF16(a, b, c) __builtin_amdgcn_mfma_f32_16x16x32_bf16((a), (b), (c), 0, 0, 0)
#define VMCNT(n) asm volatile("s_waitcnt vmcnt(" #n ")" ::: "memory")

__device__ __forceinline__ unsigned short f2bf(float f) {  // fp32 -> bf16 RNE
  unsigned int u = __float_as_uint(f);
  u += 0x7FFFu + ((u >> 16) & 1u);
  return (unsigned short)(u >> 16);
}

typedef const void __attribute__((address_space(1)))* as1_cvp;
typedef void __attribute__((address_space(3)))* as3_vp;
// Always declared (host pass parses device fns); body device-only.
__device__ __forceinline__ void gll16(const short* g, short* l) {
#if defined(__HIP_DEVICE_COMPILE__)
  __builtin_amdgcn_global_load_lds((as1_cvp)g, (as3_vp)l, 16, 0, 0);
#else
  (void)g; (void)l;
#endif
}

// ---------------- prep kernels ----------------
__global__ void count_kernel(const int* __restrict__ cm, int* __restrict__ counts) {
  __shared__ int sd[256];
  const int b = blockIdx.x, t = threadIdx.x;
  int s = 0;
  for (int i = t; i < 1024; i += 256) s += cm[b * 1024 + i];
  sd[t] = s; __syncthreads();
  for (int k = 128; k > 0; k >>= 1) { if (t < k) sd[t] += sd[t + k]; __syncthreads(); }
  if (t == 0) counts[b] = sd[0];
}

__global__ void pack_bias_kernel(const float* __restrict__ bq, const float* __restrict__ bk,
                                 const float* __restrict__ bv, float* __restrict__ dst) {
  int i = blockIdx.x * 256 + threadIdx.x;
  dst[i] = (i < 1024) ? bq[i] : (i < 2048 ? bk[i - 1024] : bv[i - 2048]);
}

// src fp32 [R][C] -> dst bf16 [C][R]
__global__ void transpose_kernel(const float* __restrict__ src, unsigned short* __restrict__ dst,
                                 int R, int C) {
  __shared__ float tile[32][33];
  const int c0 = blockIdx.x * 32, r0 = blockIdx.y * 32;
  const int tx = threadIdx.x, ty = threadIdx.y;
  #pragma unroll
  for (int i = ty; i < 32; i += 8)
    tile[i][tx] = src[(size_t)(r0 + i) * C + (c0 + tx)];
  __syncthreads();
  #pragma unroll
  for (int i = ty; i < 32; i += 8)
    dst[(size_t)(c0 + i) * R + (r0 + tx)] = f2bf(tile[tx][i]);
}

// V^T precompute: qkv [B*T][3072] (V at col 2048 + h*64) -> vtr [B*H][64][1024] bf16
__global__ void vtrans_kernel(const short* __restrict__ qkv, short* __restrict__ vtr) {
  __shared__ short tile[32][33];
  const int bh = blockIdx.z;
  const int t0 = blockIdx.x * 32, d0 = blockIdx.y * 32;
  const int b = bh >> 4, h = bh & 15;
  const int tx = threadIdx.x, ty = threadIdx.y;
  const short* src = qkv + (size_t)b * 1024 * 3072 + 2048 + h * 64;
  #pragma unroll
  for (int i = ty; i < 32; i += 8)
    tile[i][tx] = src[(size_t)(t0 + i) * 3072 + d0 + tx];
  __syncthreads();
  short* dst = vtr + (size_t)bh * 65536;
  #pragma unroll
  for (int i = ty; i < 32; i += 8)
    dst[(d0 + i) * 1024 + t0 + tx] = tile[tx][i];
}

// LayerNorm over rows of 1024 fp32 -> bf16
__global__ __launch_bounds__(256) void ln_kernel(const float* __restrict__ in,
                                                 const float* __restrict__ gw,
                                                 const float* __restrict__ bw,
                                                 unsigned short* __restrict__ out) {
  const int row = blockIdx.x, t = threadIdx.x;
  const float4 v = ((const float4*)(in + (size_t)row * 1024))[t];
  float s = v.x + v.y + v.z + v.w;
  float ss = v.x * v.x + v.y * v.y + v.z * v.z + v.w * v.w;
  #pragma unroll
  for (int o = 32; o >= 1; o >>= 1) { s += __shfl_down(s, o, 64); ss += __shfl_down(ss, o, 64); }
  __shared__ float red[8];
  if ((t & 63) == 0) { red[t >> 6] = s; red[4 + (t >> 6)] = ss; }
  __syncthreads();
  const float S  = red[0] + red[1] + red[2] + red[3];
  const float SS = red[4] + red[5] + red[6] + red[7];
  const float mu = S * (1.0f / 1024.0f);
  const float var = SS * (1.0f / 1024.0f) - mu * mu;
  const float rs = rsqrtf(var + 1e-5f);
  const int c = t * 4;
  const float4 g4 = ((const float4*)gw)[t];
  const float4 b4 = ((const float4*)bw)[t];
  us4 o4;
  o4[0] = f2bf((v.x - mu) * rs * g4.x + b4.x);
  o4[1] = f2bf((v.y - mu) * rs * g4.y + b4.y);
  o4[2] = f2bf((v.z - mu) * rs * g4.z + b4.z);
  o4[3] = f2bf((v.w - mu) * rs * g4.w + b4.w);
  *(us4*)(out + (size_t)row * 1024 + c) = o4;
}

// ---------------- GEMM 128x128 (2-phase, legacy) for fp32-out epilogues ----------------
// EPI 2: + res(fp32) -> fp32
template <int EPI>
__global__ __launch_bounds__(256) void gemm_bt_kernel(
    const short* __restrict__ A, const short* __restrict__ BT,
    const float* __restrict__ bias, int N, int K,
    unsigned short* __restrict__ outb, float* __restrict__ outf,
    const float* __restrict__ res) {
  __shared__ alignas(16) short As[4096];
  __shared__ alignas(16) short Bs[4096];
  const int t = threadIdx.x;
  const int l = t & 63, w = t >> 6;
  const int lq = l & 15, g = l >> 4;
  const int wr = w >> 1, wc = w & 1;
  const int bm = blockIdx.x * 128, bn = blockIdx.y * 128;

  const f32x4 z4 = {0.f, 0.f, 0.f, 0.f};
  f32x4 acc[4][4];
  #pragma unroll
  for (int i = 0; i < 4; i++)
    #pragma unroll
    for (int j = 0; j < 4; j++) acc[i][j] = z4;

  const short* ga = A  + (size_t)(bm + (t >> 2)) * K + (t & 3) * 8;
  const short* gb = BT + (size_t)(bn + (t >> 2)) * K + (t & 3) * 8;
  short* lA = As + w * 512;
  short* lB = Bs + w * 512;

  for (int k0 = 0; k0 < K; k0 += 32) {
    gll16(ga + k0,                  lA);
    gll16(ga + k0 + (size_t)64 * K, lA + 2048);
    gll16(gb + k0,                  lB);
    gll16(gb + k0 + (size_t)64 * K, lB + 2048);
    __syncthreads();
    short8 af[4], bfr[4];
    #pragma unroll
    for (int mi = 0; mi < 4; mi++)
      af[mi] = *(const short8*)(As + (wr * 64 + mi * 16 + lq) * 32 + 8 * g);
    #pragma unroll
    for (int ni = 0; ni < 4; ni++)
      bfr[ni] = *(const short8*)(Bs + (wc * 64 + ni * 16 + lq) * 32 + 8 * g);
    #pragma unroll
    for (int mi = 0; mi < 4; mi++)
      #pragma unroll
      for (int ni = 0; ni < 4; ni++)
        acc[mi][ni] = MFMA_BF16(af[mi], bfr[ni], acc[mi][ni]);
    __syncthreads();
  }

  #pragma unroll
  for (int mi = 0; mi < 4; mi++) {
    #pragma unroll
    for (int ni = 0; ni < 4; ni++) {
      const int col = bn + wc * 64 + ni * 16 + lq;
      const float bv = bias[col];
      #pragma unroll
      for (int r = 0; r < 4; r++) {
        const int row = bm + wr * 64 + mi * 16 + 4 * g + r;
        float v = acc[mi][ni][r] + bv;
        const size_t idx = (size_t)row * N + col;
        if (EPI == 1) v = 0.5f * v * (1.0f + erff(v * 0.70710678118654752440f));
        if (EPI == 2) outf[idx] = v + res[idx];
        else          outb[idx] = f2bf(v);
      }
    }
  }
}

// ---------------- GEMM 256x256, 8-phase, counted vmcnt (T3+T4), swizzled LDS (T2), setprio (T5) ----
// C[M,N] = A[M,K]*BT[N,K]^T + bias. EPI 0: ->bf16, EPI 1: gelu->bf16.
// 512 threads = 8 waves (2M x 4N), per-wave 128x64 output, BK=64, LDS 128KB (2 bufs).
// Stage order/iter v: Ah1(v+1), Bh1(v+1), Ah0(v+2), Bh0(v+2). vmcnt(6)@ph1, vmcnt(8)@ph4.
// Swizzle: 16B-unit ^= (row&7), applied to global SOURCE col at stage + to ds_read addr.
template <int EPI>
__global__ __launch_bounds__(512, 2) void gemm256_kernel(
    const short* __restrict__ A, const short* __restrict__ BT,
    const float* __restrict__ bias, int N, int K,
    unsigned short* __restrict__ outb) {
  __shared__ alignas(16) short lds[65536];  // [buf:32768][A/B:16384][half:8192] shorts
  const int t = threadIdx.x;
  const int l = t & 63, w = t >> 6;
  const int lq = l & 15, g = l >> 4;
  const int wr = w >> 2, wc = w & 3;
  const int bm = blockIdx.x * 256, bn = blockIdx.y * 256;
  const int NT = K >> 6;

  const int csw = ((t & 7) ^ ((t >> 3) & 7)) * 8;   // pre-swizzled global k-offset (shorts)
  const int sA = t >> 3;                             // 0..63
  const int sB = ((t >> 8) & 1) * 64 + ((t >> 3) & 31);

  const f32x4 z4 = {0.f, 0.f, 0.f, 0.f};
  f32x4 acc[8][4];
  #pragma unroll
  for (int i = 0; i < 8; i++)
    #pragma unroll
    for (int j = 0; j < 4; j++) acc[i][j] = z4;

  auto stageA = [&](int buf, int h, int k0) {
    const short* src = A + (size_t)(bm + h * 64 + sA) * K + k0 + csw;
    short* dst = lds + buf * 32768 + h * 8192 + t * 8;
    gll16(src, dst);
    gll16(src + (size_t)128 * K, dst + 4096);
  };
  auto stageB = [&](int buf, int h, int k0) {
    const short* src = BT + (size_t)(bn + h * 32 + sB) * K + k0 + csw;
    short* dst = lds + buf * 32768 + 16384 + h * 8192 + t * 8;
    gll16(src, dst);
    gll16(src + (size_t)128 * K, dst + 4096);
  };
  auto rdA = [&](int buf, int mh, int mi2, int kk) {
    const int ra = wr * 64 + mi2 * 16 + lq;
    const int unit = (kk * 4 + g) ^ (ra & 7);
    return *(const short8*)(lds + buf * 32768 + mh * 8192 + ra * 64 + unit * 8);
  };
  auto rdB = [&](int buf, int nh, int ni2, int kk) {
    const int rb = wc * 32 + ni2 * 16 + lq;
    const int unit = (kk * 4 + g) ^ (rb & 7);
    return *(const short8*)(lds + buf * 32768 + 16384 + nh * 8192 + rb * 64 + unit * 8);
  };

  // prologue: Ah0(0) Bh0(0) Ah1(0) Bh1(0) Ah0(1) Bh0(1); wait oldest 2 halves.
  stageA(0, 0, 0);  stageB(0, 0, 0);
  stageA(0, 1, 0);  stageB(0, 1, 0);
  stageA(1, 0, 64); stageB(1, 0, 64);
  VMCNT(8);
  __builtin_amdgcn_s_barrier();

  short8 a[4][2], b0[2][2], b1[2][2];
  for (int v = 0; v < NT; ++v) {
    const int cur = v & 1, nxt = cur ^ 1;
    // ---- ph1: quad (0,0) ----
    #pragma unroll
    for (int mi2 = 0; mi2 < 4; ++mi2)
      #pragma unroll
      for (int kk = 0; kk < 2; ++kk) a[mi2][kk] = rdA(cur, 0, mi2, kk);
    #pragma unroll
    for (int ni2 = 0; ni2 < 2; ++ni2)
      #pragma unroll
      for (int kk = 0; kk < 2; ++kk) b0[ni2][kk] = rdB(cur, 0, ni2, kk);
    if (v + 1 < NT) stageA(nxt, 1, (v + 1) * 64);
    if (v + 1 < NT) { VMCNT(6); } else { VMCNT(0); }
    __builtin_amdgcn_s_barrier();
    __builtin_amdgcn_s_setprio(1);
    #pragma unroll
    for (int mi2 = 0; mi2 < 4; ++mi2)
      #pragma unroll
      for (int ni2 = 0; ni2 < 2; ++ni2)
        #pragma unroll
        for (int kk = 0; kk < 2; ++kk)
          acc[mi2][ni2] = MFMA_BF16(a[mi2][kk], b0[ni2][kk], acc[mi2][ni2]);
    __builtin_amdgcn_s_setprio(0);
    __builtin_amdgcn_s_barrier();
    // ---- ph2: quad (0,1) ----
    #pragma unroll
    for (int ni2 = 0; ni2 < 2; ++ni2)
      #pragma unroll
      for (int kk = 0; kk < 2; ++kk) b1[ni2][kk] = rdB(cur, 1, ni2, kk);
    if (v + 1 < NT) stageB(nxt, 1, (v + 1) * 64);
    __builtin_amdgcn_s_barrier();
    __builtin_amdgcn_s_setprio(1);
    #pragma unroll
    for (int mi2 = 0; mi2 < 4; ++mi2)
      #pragma unroll
      for (int ni2 = 0; ni2 < 2; ++ni2)
        #pragma unroll
        for (int kk = 0; kk < 2; ++kk)
          acc[mi2][2 + ni2] = MFMA_BF16(a[mi2][kk], b1[ni2][kk], acc[mi2][2 + ni2]);
    __builtin_amdgcn_s_setprio(0);
    __builtin_amdgcn_s_barrier();
    // ---- ph3: quad (1,0) ----
    #pragma unroll
    for (int mi2 = 0; mi2 < 4; ++mi2)
      #pragma unroll
      for (int kk = 0; kk < 2; ++kk) a[mi2][kk] = rdA(cur, 1, mi2, kk);
    if (v + 2 < NT) stageA(cur, 0, (v + 2) * 64);
    __builtin_amdgcn_s_barrier();
    __builtin_amdgcn_s_setprio(1);
    #pragma unroll
    for (int mi2 = 0; mi2 < 4; ++mi2)
      #pragma unroll
      for (int ni2 = 0; ni2 < 2; ++ni2)
        #pragma unroll
        for (int kk = 0; kk < 2; ++kk)
          acc[4 + mi2][ni2] = MFMA_BF16(a[mi2][kk], b0[ni2][kk], acc[4 + mi2][ni2]);
    __builtin_amdgcn_s_setprio(0);
    __builtin_amdgcn_s_barrier();
    // ---- ph4: quad (1,1) ----
    if (v + 2 < NT) stageB(cur, 0, (v + 2) * 64);
    if (v + 1 < NT) {
      if (v + 2 < NT) { VMCNT(8); } else { VMCNT(4); }
    }
    __builtin_amdgcn_s_barrier();
    __builtin_amdgcn_s_setprio(1);
    #pragma unroll
    for (int mi2 = 0; mi2 < 4; ++mi2)
      #pragma unroll
      for (int ni2 = 0; ni2 < 2; ++ni2)
        #pragma unroll
        for (int kk = 0; kk < 2; ++kk)
          acc[4 + mi2][2 + ni2] = MFMA_BF16(a[mi2][kk], b1[ni2][kk], acc[4 + mi2][2 + ni2]);
    __builtin_amdgcn_s_setprio(0);
    __builtin_amdgcn_s_barrier();
  }

  // epilogue: bias(+gelu) -> LDS bf16 [256][256] -> coalesced dwordx4 stores
  unsigned short* eb = (unsigned short*)lds;
  #pragma unroll
  for (int mi = 0; mi < 8; ++mi) {
    #pragma unroll
    for (int ni = 0; ni < 4; ++ni) {
      const int col = wc * 64 + (ni >> 1) * 32 + (ni & 1) * 16 + lq;
      const float bv = bias[bn + col];
      #pragma unroll
      for (int r = 0; r < 4; ++r) {
        const int row = wr * 128 + (mi >> 2) * 64 + (mi & 3) * 16 + 4 * g + r;
        float vv = acc[mi][ni][r] + bv;
        if (EPI == 1) vv = 0.5f * vv * (1.0f + erff(vv * 0.70710678118654752440f));
        eb[row * 256 + col] = f2bf(vv);
      }
    }
  }
  __syncthreads();
  #pragma unroll
  for (int it = 0; it < 16; ++it) {
    const int unit = it * 512 + t;          // 16B units over 128KB
    const int row = unit >> 5, c8 = unit & 31;
    const short8 vv = *(const short8*)(lds + unit * 8);
    *(short8*)((short*)outb + (size_t)(bm + row) * N + bn + c8 * 8) = vv;
  }
}

// ---------------- flash attention: 1-wave blocks + XCD-aware bh clustering ----------------
// qkv rows [B*T][3072] = [q|k|v]; vtr [B*H][64][1024] = V^T per (b,h).
// One 64-thread block = one wave = one (pair p, bh) work item; pair owns q-tiles
// (p, 63-p) of 16 rows. blk = xcd + 8*slot, xcd = bh&7, slot = (bh>>3)*32 + p:
// all 32 pair-blocks of a bh land on one XCD (K/V L2-resident, 16 bh per XCD).
// Swapped QK^T + permuted K rows -> P^T in-lane; log2-domain softmax, defer-max;
// K/V register double-buffer prefetch.
__global__ __launch_bounds__(64) void attn_kernel(
    const short* __restrict__ qkv, const short* __restrict__ vtr,
    unsigned short* __restrict__ y, const int* __restrict__ counts) {
  const int blk = blockIdx.x;
  const int slot = blk >> 3;
  const int p = slot & 31;                      // pair index 0..31
  const int bh = ((slot >> 5) << 3) | (blk & 7);
  const int b = bh >> 4, h = bh & 15;
  const int l = threadIdx.x & 63;
  const int lq = l & 15, g = l >> 4;
  const int qb0 = p * 16, qb1 = (63 - p) * 16;
  const int count = counts[b];

  const short* base  = qkv + (size_t)b * 1024 * 3072 + h * 64;
  const short* vbase = vtr + (size_t)bh * 65536;

  short8 qf[2][2];  // [group][k-half]; B-operand col q = qb[grp]+lq
  {
    const short* qr0 = base + (size_t)(qb0 + lq) * 3072 + 8 * g;
    const short* qr1 = base + (size_t)(qb1 + lq) * 3072 + 8 * g;
    qf[0][0] = *(const short8*)qr0; qf[0][1] = *(const short8*)(qr0 + 32);
    qf[1][0] = *(const short8*)qr1; qf[1][1] = *(const short8*)(qr1 + 32);
  }

  const f32x4 z4 = {0.f, 0.f, 0.f, 0.f};
  f32x4 oacc[2][4];  // [group][dc]: O^T[d=16dc+4g+r][q]
  #pragma unroll
  for (int grp = 0; grp < 2; ++grp)
    #pragma unroll
    for (int dc = 0; dc < 4; ++dc) oacc[grp][dc] = z4;
  float mrun[2] = {-1e30f, -1e30f};
  float lrun[2] = {0.f, 0.f};
  const int permrow = 8 * (lq >> 2) + (lq & 3);  // K-row perm -> P^T in-lane
  const float SC = 0.125f * 1.44269504088896f;   // 1/sqrt(D) * log2(e)

  const int ncond = min((count + 31) >> 5, 8);
  const int ncausal = (qb1 + 16 - 256 + 31) >> 5;
  const int nt = ncond + ncausal;
  auto kv_of = [&](int i) { return i < ncond ? i * 32 : 256 + (i - ncond) * 32; };

  auto loadt = [&](int kv0, short8 (&kr)[4], short8 (&vr)[4]) {
    const short* ka = base + (size_t)(kv0 + permrow) * 3072 + 1024 + 8 * g;
    kr[0] = *(const short8*)ka;
    kr[1] = *(const short8*)(ka + 32);
    kr[2] = *(const short8*)(ka + 4 * 3072);
    kr[3] = *(const short8*)(ka + 4 * 3072 + 32);
    #pragma unroll
    for (int dc = 0; dc < 4; ++dc)
      vr[dc] = *(const short8*)(vbase + (16 * dc + lq) * 1024 + kv0 + 8 * g);
  };

  auto compute = [&](int i, const short8 (&kr)[4], const short8 (&vr)[4]) {
    const int kv0 = kv_of(i);
    const bool isCond = (i < ncond);
    #pragma unroll
    for (int grp = 0; grp < 2; ++grp) {
      const int qb = grp ? qb1 : qb0;
      if (!isCond && kv0 >= qb + 16) continue;  // group inactive (wave-uniform)
      const bool needMask = isCond ? (kv0 + 32 > count) : (kv0 + 31 > qb);
      f32x4 sA = z4, sB = z4;  // S^T: reg r = kv0+8g+r (A) / +4 (B), col q
      __builtin_amdgcn_s_setprio(1);
      sA = MFMA_BF16(kr[0], qf[grp][0], sA);
      sA = MFMA_BF16(kr[1], qf[grp][1], sA);
      sB = MFMA_BF16(kr[2], qf[grp][0], sB);
      sB = MFMA_BF16(kr[3], qf[grp][1], sB);
      __builtin_amdgcn_s_setprio(0);
      const int q = qb + lq;
      float mx = -1e30f;
      if (needMask) {
        #pragma unroll
        for (int r = 0; r < 4; ++r) {
          const int colA = kv0 + 8 * g + r, colB = colA + 4;
          const bool okA = isCond ? (colA < count) : (colA <= q);
          const bool okB = isCond ? (colB < count) : (colB <= q);
          const float vA = okA ? sA[r] * SC : -1e30f;
          const float vB = okB ? sB[r] * SC : -1e30f;
          sA[r] = vA; sB[r] = vB;
          mx = fmaxf(fmaxf(vA, vB), mx);
        }
      } else {
        #pragma unroll
        for (int r = 0; r < 4; ++r) {
          const float vA = sA[r] * SC, vB = sB[r] * SC;
          sA[r] = vA; sB[r] = vB;
          mx = fmaxf(fmaxf(vA, vB), mx);
        }
      }
      mx = fmaxf(mx, __shfl_xor(mx, 16, 64));
      mx = fmaxf(mx, __shfl_xor(mx, 32, 64));
      float m = mrun[grp];
      if (!__all(mx <= m + 8.0f)) {   // defer-max: rescale only on real growth
        const float mn = fmaxf(m, mx);
        const float sf = exp2f(m - mn);
        lrun[grp] *= sf;
        #pragma unroll
        for (int dc = 0; dc < 4; ++dc)
          #pragma unroll
          for (int r = 0; r < 4; ++r) oacc[grp][dc][r] *= sf;
        mrun[grp] = mn; m = mn;
      }
      float ps = 0.f;
      #pragma unroll
      for (int r = 0; r < 4; ++r) {
        const float aa = exp2f(sA[r] - m);
        const float c2 = exp2f(sB[r] - m);
        sA[r] = aa; sB[r] = c2; ps += aa + c2;
      }
      ps += __shfl_xor(ps, 16, 64);
      ps += __shfl_xor(ps, 32, 64);
      lrun[grp] += ps;
      union { short8 s8; __hip_bfloat162 h2[4]; } pu;  // P^T: elem j -> kv0+8g+j
      pu.h2[0] = __float22bfloat162_rn(float2{sA[0], sA[1]});
      pu.h2[1] = __float22bfloat162_rn(float2{sA[2], sA[3]});
      pu.h2[2] = __float22bfloat162_rn(float2{sB[0], sB[1]});
      pu.h2[3] = __float22bfloat162_rn(float2{sB[2], sB[3]});
      __builtin_amdgcn_s_setprio(1);
      #pragma unroll
      for (int dc = 0; dc < 4; ++dc)
        oacc[grp][dc] = MFMA_BF16(vr[dc], pu.s8, oacc[grp][dc]);
      __builtin_amdgcn_s_setprio(0);
    }
  };

  short8 kb0[4], vb0[4], kb1[4], vb1[4];
  loadt(kv_of(0), kb0, vb0);
  for (int i = 0; i < nt; i += 2) {
    if (i + 1 < nt) loadt(kv_of(i + 1), kb1, vb1);
    compute(i, kb0, vb0);
    if (i + 1 >= nt) break;
    if (i + 2 < nt) loadt(kv_of(i + 2), kb0, vb0);
    compute(i + 1, kb1, vb1);
  }

  #pragma unroll
  for (int grp = 0; grp < 2; ++grp) {
    const int qb = grp ? qb1 : qb0;
    const float inv = 1.0f / lrun[grp];
    unsigned short* yr = y + (size_t)(b * 1024 + qb + lq) * 1024 + h * 64;
    #pragma unroll
    for (int dc = 0; dc < 4; ++dc)
      #pragma unroll
      for (int r = 0; r < 4; ++r)
        yr[16 * dc + 4 * g + r] = f2bf(oacc[grp][dc][r] * inv);
  }
}

// ---------------- launch ----------------
extern "C" void kernel_launch(void* const* d_in, const int* in_sizes, int n_in,
                              void* d_out, int out_size, void* d_ws, size_t ws_size,
                              hipStream_t stream) {
  (void)in_sizes; (void)n_in; (void)out_size; (void)ws_size;
  const float* x     = (const float*)d_in[0];
  const float* ln1_g = (const float*)d_in[1];
  const float* ln1_b = (const float*)d_in[2];
  const float* Wq    = (const float*)d_in[3];
  const float* bq    = (const float*)d_in[4];
  const float* Wk    = (const float*)d_in[5];
  const float* bk    = (const float*)d_in[6];
  const float* Wv    = (const float*)d_in[7];
  const float* bv    = (const float*)d_in[8];
  const float* Wp    = (const float*)d_in[9];
  const float* bp    = (const float*)d_in[10];
  const float* ln2_g = (const float*)d_in[11];
  const float* ln2_b = (const float*)d_in[12];
  const float* W1    = (const float*)d_in[13];
  const float* b1    = (const float*)d_in[14];
  const float* W2    = (const float*)d_in[15];
  const float* b2    = (const float*)d_in[16];
  const int* cond_mask = (const int*)d_in[17];

  char* ws = (char*)d_ws;
  const size_t MB = 1u << 20;
  short* xn    = (short*)(ws + 0);
  short* vtr   = (short*)(ws + 0);
  short* qkv   = (short*)(ws + 16 * MB);
  short* act   = (short*)(ws + 0);
  unsigned short* yb = (unsigned short*)(ws + 64 * MB);
  float* x1    = (float*)(ws + 80 * MB);
  short* hb    = (short*)(ws + 112 * MB);
  short* wqkvT = (short*)(ws + 128 * MB);
  short* wpT   = (short*)(ws + 134 * MB);
  short* w1T   = (short*)(ws + 136 * MB);
  short* w2T   = (short*)(ws + 144 * MB);
  float* bqkv  = (float*)(ws + 152 * MB);
  int* counts  = (int*)(ws + 152 * MB + 16384);

  const dim3 tb(32, 8);
  count_kernel<<<8, 256, 0, stream>>>(cond_mask, counts);
  pack_bias_kernel<<<12, 256, 0, stream>>>(bq, bk, bv, bqkv);
  transpose_kernel<<<dim3(32, 32), tb, 0, stream>>>(Wq, (unsigned short*)wqkvT, 1024, 1024);
  transpose_kernel<<<dim3(32, 32), tb, 0, stream>>>(Wk, (unsigned short*)(wqkvT + 1024 * 1024), 1024, 1024);
  transpose_kernel<<<dim3(32, 32), tb, 0, stream>>>(Wv, (unsigned short*)(wqkvT + 2 * 1024 * 1024), 1024, 1024);
  transpose_kernel<<<dim3(32, 32), tb, 0, stream>>>(Wp, (unsigned short*)wpT, 1024, 1024);
  transpose_kernel<<<dim3(128, 32), tb, 0, stream>>>(W1, (unsigned short*)w1T, 1024, 4096);
  transpose_kernel<<<dim3(32, 128), tb, 0, stream>>>(W2, (unsigned short*)w2T, 4096, 1024);
  ln_kernel<<<8192, 256, 0, stream>>>(x, ln1_g, ln1_b, (unsigned short*)xn);

  gemm256_kernel<0><<<dim3(32, 12), 512, 0, stream>>>(xn, wqkvT, bqkv, 3072, 1024,
                                                      (unsigned short*)qkv);
  vtrans_kernel<<<dim3(32, 2, 128), tb, 0, stream>>>(qkv, vtr);
  attn_kernel<<<4096, 64, 0, stream>>>(qkv, vtr, yb, counts);
  gemm_bt_kernel<2><<<dim3(64, 8), 256, 0, stream>>>((const short*)yb, wpT, bp, 1024, 1024,
                                                     nullptr, x1, x);
  ln_kernel<<<8192, 256, 0, stream>>>(x1, ln2_g, ln2_b, (unsigned short*)hb);
  gemm256_kernel<1><<<dim3(32, 16), 512, 0, stream>>>(hb, w1T, b1, 4096, 1024,
                                                      (unsigned short*)act);
  gemm_bt_kernel<2><<<dim3(64, 8), 256, 0, stream>>>(act, w2T, b2, 1024, 4096,
                                                     nullptr, (float*)d_out, x1);
}